// Round 2
// baseline (2126.740 us; speedup 1.0000x reference)
//
#include <hip/hip_runtime.h>

// SVRSheafNet forward on MI355X. All float inputs are FP32 (per reference),
// edge_index int32, output FP32. Internals fp32; bf16 only at MFMA inputs.
// ws usage ~172 MB.

constexpr int N = 50000;
constexpr int E = 512000;
constexpr int IN = 512;
constexpr int H = 128;
constexpr float DT = 0.1f;
constexpr float EPSC = 1e-3f;
constexpr float TOL2 = 1e-8f;
constexpr int MAXITER = 20;

typedef __attribute__((ext_vector_type(8))) short bf16x8;
typedef __attribute__((ext_vector_type(4))) float f32x4;

__device__ inline short f2b(float f){ unsigned u; __builtin_memcpy(&u,&f,4); unsigned r = u + 0x7FFFu + ((u>>16)&1u); return (short)(r>>16); }

// ---------------- fp32 -> bf16 conversions ----------------
__global__ void conv_x(const float* __restrict__ A, short* __restrict__ out, long total4){
  long idx = (long)blockIdx.x*256 + threadIdx.x;
  if (idx < total4){
    float4 v = ((const float4*)A)[idx];
    short4 o; o.x=f2b(v.x); o.y=f2b(v.y); o.z=f2b(v.z); o.w=f2b(v.w);
    ((short4*)out)[idx] = o;
  }
}

// B[K][Nc] fp32 -> Bt[Nc][K] bf16
__global__ void conv_transpose(const float* __restrict__ B, short* __restrict__ Bt, int K, int Nc){
  int id = blockIdx.x*256 + threadIdx.x;
  if (id < K*Nc){ int k = id / Nc, n = id - k*Nc; Bt[(long)n*K + k] = f2b(B[id]); }
}

// ---------------- MFMA GEMM: A[M,K]bf16 @ Bt[TN,K]bf16 -> C[M,TN]f32 ----------------
template<int K, int TN>
__global__ __launch_bounds__(256) void mfma_gemm(const short* __restrict__ A, const short* __restrict__ Bt,
                                                 float* __restrict__ C, int M){
  constexpr int NT = TN/16;
  __shared__ short lA[64][40];
  __shared__ short lB[TN][40];
  int wid = threadIdx.x >> 6, lane = threadIdx.x & 63;
  int ln15 = lane & 15, quad = lane >> 4;
  int m0 = blockIdx.x * 64;
  f32x4 acc[NT];
  #pragma unroll
  for (int t=0;t<NT;t++) acc[t] = (f32x4){0.f,0.f,0.f,0.f};
  for (int k0=0; k0<K; k0+=32){
    {
      int row = threadIdx.x >> 2, q = threadIdx.x & 3;
      int gr = m0 + row;
      uint4 v = {0u,0u,0u,0u};
      if (gr < M) v = *(const uint4*)(A + (long)gr*K + k0 + q*8);
      *(uint4*)&lA[row][q*8] = v;
    }
    if constexpr (TN==128){
      int row = threadIdx.x >> 1, hh = threadIdx.x & 1;
      const uint4* src = (const uint4*)(Bt + (long)row*K + k0 + hh*16);
      *(uint4*)&lB[row][hh*16]   = src[0];
      *(uint4*)&lB[row][hh*16+8] = src[1];
    } else {
      int row = threadIdx.x >> 2, q = threadIdx.x & 3;
      *(uint4*)&lB[row][q*8] = *(const uint4*)(Bt + (long)row*K + k0 + q*8);
    }
    __syncthreads();
    bf16x8 a = *(bf16x8*)&lA[wid*16+ln15][quad*8];
    #pragma unroll
    for (int t=0;t<NT;t++){
      bf16x8 b = *(bf16x8*)&lB[t*16+ln15][quad*8];
      acc[t] = __builtin_amdgcn_mfma_f32_16x16x32_bf16(a, b, acc[t], 0, 0, 0);
    }
    __syncthreads();
  }
  int mr = m0 + wid*16 + quad*4;
  #pragma unroll
  for (int t=0;t<NT;t++){
    #pragma unroll
    for (int r=0;r<4;r++){
      int gr = mr + r;
      if (gr < M) C[(long)gr*TN + t*16 + ln15] = acc[t][r];
    }
  }
}

// ---------------- LayerNorm + sigmoid; writes fp32 h and bf16 h ----------------
__global__ void ln_sigmoid(const float* __restrict__ pre, const float* __restrict__ b_in,
                           const float* __restrict__ g, const float* __restrict__ bb,
                           float* __restrict__ h, short* __restrict__ hbf){
  int row = blockIdx.x; int t = threadIdx.x; // 128 threads
  float v = pre[(long)row*H + t] + b_in[t];
  __shared__ float sm[2];
  int lane = t & 63, wid = t >> 6;
  float x = v;
  #pragma unroll
  for (int d=32; d; d>>=1) x += __shfl_xor(x, d);
  if (lane==0) sm[wid] = x;
  __syncthreads();
  float mean = (sm[0]+sm[1]) * (1.f/128.f);
  float dv = v - mean;
  __syncthreads();
  x = dv*dv;
  #pragma unroll
  for (int d=32; d; d>>=1) x += __shfl_xor(x, d);
  if (lane==0) sm[wid] = x;
  __syncthreads();
  float var = (sm[0]+sm[1]) * (1.f/128.f);
  float y = dv * rsqrtf(var + 1e-5f) * g[t] + bb[t];
  float hv = 1.f/(1.f+expf(-y));
  h[(long)row*H+t] = hv;
  hbf[(long)row*H+t] = f2b(hv);
}

// ---------------- CSR build ----------------
__global__ void count_deg(const int* __restrict__ ei, int* cntb, int* cnti){
  int e = blockIdx.x*256 + threadIdx.x;
  if (e < E){
    int r = ei[e], c = ei[E+e];
    atomicAdd(&cntb[r],1); atomicAdd(&cntb[c],1); atomicAdd(&cnti[c],1);
  }
}

__global__ __launch_bounds__(1024) void scan_excl(const int* __restrict__ cnt, int n, int* __restrict__ off){
  __shared__ int ws_[16];
  __shared__ int carry;
  if (threadIdx.x==0) carry = 0;
  __syncthreads();
  int lane = threadIdx.x & 63, wid = threadIdx.x >> 6;
  for (int base=0; base<n; base += 1024){
    int i = base + threadIdx.x;
    int v = (i<n) ? cnt[i] : 0;
    int x = v;
    #pragma unroll
    for (int d=1; d<64; d<<=1){ int y = __shfl_up(x, d); if (lane>=d) x += y; }
    if (lane==63) ws_[wid] = x;
    __syncthreads();
    if (threadIdx.x==0){ int acc=0; for (int w=0;w<16;w++){ int t=ws_[w]; ws_[w]=acc; acc+=t; } }
    __syncthreads();
    int excl = carry + ws_[wid] + x - v;
    if (i<n) off[i] = excl;
    __syncthreads();
    if (threadIdx.x==1023) carry = carry + ws_[15] + x;
    __syncthreads();
  }
  if (threadIdx.x==0) off[n] = carry;
}

__global__ void fill_adj(const int* __restrict__ ei, const int* __restrict__ offb, const int* __restrict__ offi,
                         int* curb, int* curi, int* adjn, int* adjeid, int* adjsrc){
  int e = blockIdx.x*256 + threadIdx.x;
  if (e < E){
    int r = ei[e], c = ei[E+e];
    int p = offb[r] + atomicAdd(&curb[r],1); adjn[p]=c; adjeid[p]=e;
    p     = offb[c] + atomicAdd(&curb[c],1); adjn[p]=r; adjeid[p]=e;
    p     = offi[c] + atomicAdd(&curi[c],1); adjsrc[p]=r;
  }
}

__global__ void adj_weights(const int* __restrict__ adjeid, const float* __restrict__ wL, float* __restrict__ adjw){
  int p = blockIdx.x*256 + threadIdx.x;
  if (p < 2*E) adjw[p] = wL[adjeid[p]];
}

// ---------------- per-edge sheaf weights ----------------
__global__ void edge_weights(const int* __restrict__ ei, const float* __restrict__ hw,
                             float* __restrict__ wL, float* __restrict__ deg){
  int wid = threadIdx.x >> 6, lane = threadIdx.x & 63;
  int e = blockIdx.x*4 + wid;
  if (e >= E) return;
  int r = ei[e], c = ei[E+e];
  const float2* Hc = (const float2*)hw;
  float2 fr = Hc[(long)r*64 + lane];
  float2 fc = Hc[(long)c*64 + lane];
  float dx = fr.x-fc.x, dy = fr.y-fc.y;
  float sd = dx*dx + dy*dy;
  float sr = fr.x*fr.x + fr.y*fr.y;
  #pragma unroll
  for (int d=32; d; d>>=1){ sd += __shfl_xor(sd,d); sr += __shfl_xor(sr,d); }
  if (lane==0){
    float C  = sd * (1.0f/128.0f);
    float P0 = fminf(fmaxf(expf(-C*(1.0f/EPSC)), 1e-3f), 1.0f);
    float Ps = fminf(fmaxf(expf(logf(P0+1e-12f) - C*(1.0f/EPSC)), 1e-3f), 1.0f);
    float w  = 0.7f*P0 + 0.3f*Ps;
    float wl = w*w*sr*(1.0f/128.0f);
    wL[e] = wl;
    atomicAdd(&deg[r], wl);
    atomicAdd(&deg[c], wl);
  }
}

// ---------------- CG ----------------
__global__ void cg_init(const float* __restrict__ h, float* __restrict__ X, float* __restrict__ R,
                        float* __restrict__ P, float* __restrict__ rs0){
  __shared__ float cols[128];
  if (threadIdx.x < 128) cols[threadIdx.x] = 0.f;
  __syncthreads();
  int total = N*32;
  float4 z = {0,0,0,0};
  for (int idx = blockIdx.x*blockDim.x + threadIdx.x; idx < total; idx += gridDim.x*blockDim.x){
    float4 hv = ((const float4*)h)[idx];
    ((float4*)X)[idx] = z; ((float4*)R)[idx] = hv; ((float4*)P)[idx] = hv;
    int c4 = (idx & 31)*4;
    atomicAdd(&cols[c4+0], hv.x*hv.x);
    atomicAdd(&cols[c4+1], hv.y*hv.y);
    atomicAdd(&cols[c4+2], hv.z*hv.z);
    atomicAdd(&cols[c4+3], hv.w*hv.w);
  }
  __syncthreads();
  if (threadIdx.x < 128){ float v = cols[threadIdx.x]; if (v != 0.f) atomicAdd(&rs0[threadIdx.x], v); }
}

__global__ void cg_ap(const int* __restrict__ flags, int k, const float* __restrict__ P,
                      const int* __restrict__ offb, const int* __restrict__ adjn, const float* __restrict__ adjw,
                      const float* __restrict__ deg, float* __restrict__ AP, float* __restrict__ dn){
  if (flags[k]) return;
  __shared__ float cols[128];
  if (threadIdx.x < 128) cols[threadIdx.x] = 0.f;
  __syncthreads();
  int wid = threadIdx.x >> 6, lane = threadIdx.x & 63;
  int node = blockIdx.x*4 + wid;
  if (node < N){
    const float2* Pc = (const float2*)P;
    float2 acc = {0.f,0.f};
    int p0 = offb[node], p1 = offb[node+1];
    for (int p=p0; p<p1; p++){
      int j = adjn[p]; float w = adjw[p];
      float2 pj = Pc[(long)j*64 + lane];
      acc.x += w*pj.x; acc.y += w*pj.y;
    }
    float dg = deg[node];
    float2 pi = Pc[(long)node*64 + lane];
    float2 ap;
    ap.x = pi.x + DT*(dg*pi.x - acc.x);
    ap.y = pi.y + DT*(dg*pi.y - acc.y);
    ((float2*)AP)[(long)node*64 + lane] = ap;
    atomicAdd(&cols[lane*2],   pi.x*ap.x);
    atomicAdd(&cols[lane*2+1], pi.y*ap.y);
  }
  __syncthreads();
  if (threadIdx.x < 128){ float v = cols[threadIdx.x]; if (v != 0.f) atomicAdd(&dn[threadIdx.x], v); }
}

__global__ void cg_xr(const int* __restrict__ flags, int k, const float* __restrict__ rs, const float* __restrict__ dn,
                      const float* __restrict__ P, const float* __restrict__ AP,
                      float* __restrict__ X, float* __restrict__ R, float* __restrict__ rsn){
  if (flags[k]) return;
  __shared__ float cols[128];
  if (threadIdx.x < 128) cols[threadIdx.x] = 0.f;
  __syncthreads();
  int total = N*32;
  for (int idx = blockIdx.x*blockDim.x + threadIdx.x; idx < total; idx += gridDim.x*blockDim.x){
    int c4 = (idx & 31)*4;
    float a0 = rs[c4+0]/(dn[c4+0]+1e-16f);
    float a1 = rs[c4+1]/(dn[c4+1]+1e-16f);
    float a2 = rs[c4+2]/(dn[c4+2]+1e-16f);
    float a3 = rs[c4+3]/(dn[c4+3]+1e-16f);
    float4 p  = ((const float4*)P)[idx];
    float4 ap = ((const float4*)AP)[idx];
    float4 x  = ((float4*)X)[idx];
    float4 r  = ((float4*)R)[idx];
    x.x += a0*p.x; x.y += a1*p.y; x.z += a2*p.z; x.w += a3*p.w;
    r.x -= a0*ap.x; r.y -= a1*ap.y; r.z -= a2*ap.z; r.w -= a3*ap.w;
    ((float4*)X)[idx] = x; ((float4*)R)[idx] = r;
    atomicAdd(&cols[c4+0], r.x*r.x);
    atomicAdd(&cols[c4+1], r.y*r.y);
    atomicAdd(&cols[c4+2], r.z*r.z);
    atomicAdd(&cols[c4+3], r.w*r.w);
  }
  __syncthreads();
  if (threadIdx.x < 128){ float v = cols[threadIdx.x]; if (v != 0.f) atomicAdd(&rsn[threadIdx.x], v); }
}

__global__ void cg_p(const int* __restrict__ flags, int k, const float* __restrict__ rsn, const float* __restrict__ rsp,
                     const float* __restrict__ R, float* __restrict__ P, int* __restrict__ flags_w){
  if (flags[k]){ if (threadIdx.x==0) flags_w[k+1] = 1; return; }
  __shared__ float red[4];
  __shared__ int done_s;
  float v = (threadIdx.x < 128) ? rsn[threadIdx.x] : -1.f;
  #pragma unroll
  for (int d=32; d; d>>=1) v = fmaxf(v, __shfl_xor(v, d));
  if ((threadIdx.x & 63)==0) red[threadIdx.x>>6] = v;
  __syncthreads();
  if (threadIdx.x==0){
    float m = fmaxf(fmaxf(red[0],red[1]), fmaxf(red[2],red[3]));
    done_s = (m < TOL2) ? 1 : 0;
  }
  __syncthreads();
  if (done_s){ if (threadIdx.x==0) flags_w[k+1] = 1; return; }
  int total = N*32;
  for (int idx = blockIdx.x*blockDim.x + threadIdx.x; idx < total; idx += gridDim.x*blockDim.x){
    int c4 = (idx & 31)*4;
    float b0 = rsn[c4+0]/(rsp[c4+0]+1e-16f);
    float b1v = rsn[c4+1]/(rsp[c4+1]+1e-16f);
    float b2v = rsn[c4+2]/(rsp[c4+2]+1e-16f);
    float b3 = rsn[c4+3]/(rsp[c4+3]+1e-16f);
    float4 r = ((const float4*)R)[idx];
    float4 p = ((float4*)P)[idx];
    p.x = r.x + b0*p.x; p.y = r.y + b1v*p.y; p.z = r.z + b2v*p.z; p.w = r.w + b3*p.w;
    ((float4*)P)[idx] = p;
  }
}

// ---------------- AFM ----------------
__global__ void isd_kernel(const float* __restrict__ deg, float* __restrict__ isd){
  int i = blockIdx.x*256 + threadIdx.x;
  if (i < N) isd[i] = sqrtf(1.f / fmaxf(deg[i], 1e-8f));
}

__global__ void tl_apply(const float* __restrict__ Min, const float* __restrict__ Mprev, float alpha, float beta,
                         const float* __restrict__ isd, const float* __restrict__ deg, const int* __restrict__ offb,
                         const int* __restrict__ adjn, const float* __restrict__ adjw, float* __restrict__ out){
  int wid = threadIdx.x >> 6, lane = threadIdx.x & 63;
  int node = blockIdx.x*4 + wid;
  if (node >= N) return;
  const float2* Mc = (const float2*)Min;
  const float2* Pv = (const float2*)Mprev;
  float2 acc = {0.f,0.f};
  int p0 = offb[node], p1 = offb[node+1];
  for (int p=p0; p<p1; p++){
    int j = adjn[p]; float w = adjw[p]*isd[j];
    float2 mj = Mc[(long)j*64 + lane];
    acc.x += w*mj.x; acc.y += w*mj.y;
  }
  float ii = isd[node]; float dg = deg[node];
  float2 mi = Mc[(long)node*64 + lane];
  float2 pv = Pv[(long)node*64 + lane];
  float2 o;
  o.x = alpha*(mi.x + ii*(dg*ii*mi.x - acc.x)) - beta*pv.x;
  o.y = alpha*(mi.y + ii*(dg*ii*mi.y - acc.y)) - beta*pv.y;
  ((float2*)out)[(long)node*64 + lane] = o;
}

__global__ void combine_fused(const float* __restrict__ h, const float* __restrict__ X,
                              const float* __restrict__ T1, const float* __restrict__ T2, const float* __restrict__ T3,
                              const float* __restrict__ gamma, const float* __restrict__ asvr, const float* __restrict__ aafm,
                              short* __restrict__ fusedb){
  float g0=gamma[0], g1=gamma[1], g2=gamma[2], g3=gamma[3];
  float mg = fmaxf(fmaxf(g0,g1), fmaxf(g2,g3));
  float e0=expf(g0-mg), e1=expf(g1-mg), e2=expf(g2-mg), e3=expf(g3-mg);
  float s = e0+e1+e2+e3;
  float a0=e0/s, a1=e1/s, a2=e2/s, a3=e3/s;
  float s1 = 1.f/(1.f+expf(-asvr[0]));
  float s2 = 1.f/(1.f+expf(-aafm[0]));
  int total = N*H;
  for (int i = blockIdx.x*blockDim.x + threadIdx.x; i < total; i += gridDim.x*blockDim.x){
    float hv = h[i];
    float v = hv + s1*X[i] + s2*(a0*hv + a1*T1[i] + a2*T2[i] + a3*T3[i]);
    fusedb[i] = f2b(v);
  }
}

// ---------------- GAT ----------------
__global__ void esed1_kernel(const float* __restrict__ xw1, const float* __restrict__ a1s, const float* __restrict__ a1d,
                             float* __restrict__ es, float* __restrict__ ed){
  int id = blockIdx.x*256 + threadIdx.x;
  if (id < N*8){
    int n = id >> 3, hd = id & 7;
    const float* xr = xw1 + (long)n*64 + hd*8;
    float s=0.f, d=0.f;
    #pragma unroll
    for (int c=0;c<8;c++){ float v = xr[c]; s += v*a1s[hd*8+c]; d += v*a1d[hd*8+c]; }
    es[id]=s; ed[id]=d;
  }
}

__global__ void gat1(const int* __restrict__ offi, const int* __restrict__ adjsrc,
                     const float* __restrict__ es, const float* __restrict__ ed,
                     const float* __restrict__ xw1, const float* __restrict__ b1, float* __restrict__ o1){
  int wid = threadIdx.x >> 6, lane = threadIdx.x & 63;
  int d = blockIdx.x*4 + wid;
  if (d >= N) return;
  int hd = lane >> 3;
  float edd = ed[d*8+hd];
  float esd = es[d*8+hd];
  auto lk = [](float x){ return x >= 0.f ? x : 0.2f*x; };
  float m = lk(esd+edd);
  int p0 = offi[d], p1 = offi[d+1];
  for (int p=p0; p<p1; p++){
    int s = adjsrc[p];
    m = fmaxf(m, lk(es[s*8+hd]+edd));
  }
  float ex = expf(lk(esd+edd)-m);
  float den = ex;
  float num = ex * xw1[(long)d*64 + lane];
  for (int p=p0; p<p1; p++){
    int s = adjsrc[p];
    float e2v = expf(lk(es[s*8+hd]+edd)-m);
    den += e2v;
    num += e2v * xw1[(long)s*64 + lane];
  }
  float o = num/(den+1e-16f) + b1[lane];
  o1[(long)d*64+lane] = o > 0.f ? o : expm1f(o);
}

__global__ void xw2_kernel(const float* __restrict__ o1, const float* __restrict__ W2, float* __restrict__ xw2){
  __shared__ float w2s[64*16];
  for (int i=threadIdx.x; i<64*16; i+=256) w2s[i] = W2[i];
  __syncthreads();
  int id = blockIdx.x*256 + threadIdx.x;
  if (id < N*16){
    int n = id >> 4, c = id & 15;
    const float* orow = o1 + (long)n*64;
    float acc = 0.f;
    #pragma unroll
    for (int kk=0; kk<64; kk++) acc += orow[kk]*w2s[kk*16+c];
    xw2[id] = acc;
  }
}

__global__ void esed2_kernel(const float* __restrict__ xw2, const float* __restrict__ a2s, const float* __restrict__ a2d,
                             float* __restrict__ es2, float* __restrict__ ed2){
  int n = blockIdx.x*256 + threadIdx.x;
  if (n < N){
    float s=0.f, d=0.f;
    #pragma unroll
    for (int c=0;c<16;c++){ float v = xw2[(long)n*16+c]; s += v*a2s[c]; d += v*a2d[c]; }
    es2[n]=s; ed2[n]=d;
  }
}

__global__ void gat2(const int* __restrict__ offi, const int* __restrict__ adjsrc,
                     const float* __restrict__ es2, const float* __restrict__ ed2,
                     const float* __restrict__ xw2, const float* __restrict__ b2w, float* __restrict__ out){
  int wid = threadIdx.x >> 6, lane = threadIdx.x & 63;
  int d = blockIdx.x*4 + wid;
  if (d >= N) return;
  auto lk = [](float x){ return x >= 0.f ? x : 0.2f*x; };
  float edd = ed2[d];
  float m = lk(es2[d]+edd);
  int p0 = offi[d], p1 = offi[d+1];
  for (int p=p0; p<p1; p++) m = fmaxf(m, lk(es2[adjsrc[p]]+edd));
  float ex = expf(lk(es2[d]+edd)-m);
  float den = ex;
  float num = (lane<16) ? ex*xw2[(long)d*16+lane] : 0.f;
  for (int p=p0; p<p1; p++){
    int s = adjsrc[p];
    float e2v = expf(lk(es2[s]+edd)-m);
    den += e2v;
    if (lane<16) num += e2v*xw2[(long)s*16+lane];
  }
  if (lane<16) out[(long)d*16+lane] = num/(den+1e-16f) + b2w[lane];
}

// ---------------- host ----------------
extern "C" void kernel_launch(void* const* d_in, const int* in_sizes, int n_in,
                              void* d_out, int out_size, void* d_ws, size_t ws_size,
                              hipStream_t stream){
  const float* x     = (const float*)d_in[0];
  const int*   ei    = (const int*)  d_in[1];
  const float* W_in  = (const float*)d_in[2];
  const float* b_in  = (const float*)d_in[3];
  const float* ln_g  = (const float*)d_in[4];
  const float* ln_b  = (const float*)d_in[5];
  const float* W_sh  = (const float*)d_in[6];
  const float* gamma = (const float*)d_in[7];
  const float* asvr  = (const float*)d_in[8];
  const float* aafm  = (const float*)d_in[9];
  const float* W1    = (const float*)d_in[10];
  const float* a1s   = (const float*)d_in[11];
  const float* a1d   = (const float*)d_in[12];
  const float* b1    = (const float*)d_in[13];
  const float* W2    = (const float*)d_in[14];
  const float* a2s   = (const float*)d_in[15];
  const float* a2d   = (const float*)d_in[16];
  const float* b2w   = (const float*)d_in[17];

  char* ws = (char*)d_ws;
  size_t off = 0;
  auto alloc = [&](size_t bytes)->char*{ char* p = ws + off; off = (off + bytes + 255) & ~(size_t)255; return p; };
  float* h    = (float*)alloc((size_t)N*H*4);
  float* big1 = (float*)alloc((size_t)N*H*4); // preLN -> hw -> AP -> T3
  float* X    = (float*)alloc((size_t)N*H*4);
  float* Rb   = (float*)alloc((size_t)N*H*4); // R -> T1
  float* Pb   = (float*)alloc((size_t)N*H*4); // P -> T2
  short* hbf  = (short*)alloc((size_t)N*H*2);
  short* fusedb = (short*)alloc((size_t)N*H*2);
  float* wLp  = (float*)alloc((size_t)E*4);
  float* deg  = (float*)alloc((size_t)N*4);
  float* isd  = (float*)alloc((size_t)N*4);
  int* cntb   = (int*)alloc((size_t)N*4);
  int* cnti   = (int*)alloc((size_t)N*4);
  int* offb   = (int*)alloc((size_t)(N+1)*4);
  int* offi   = (int*)alloc((size_t)(N+1)*4);
  int* adjn   = (int*)alloc((size_t)2*E*4);
  int* adjeid = (int*)alloc((size_t)2*E*4);
  float* adjw = (float*)alloc((size_t)2*E*4);
  int* adjsrc = (int*)alloc((size_t)E*4);
  short* BtIn = (short*)alloc((size_t)IN*H*2);
  short* Wst  = (short*)alloc((size_t)H*H*2);
  short* W1t  = (short*)alloc((size_t)H*64*2);
  float* rs_all = (float*)alloc((size_t)(MAXITER+1)*128*4);
  float* dn_all = (float*)alloc((size_t)MAXITER*128*4);
  int* flags  = (int*)alloc((size_t)(MAXITER+1)*4);

  // aliases (regions dead by the time these are written)
  short* xbf = (short*)X;               // N*IN bf16 = 51.2MB, spans X+Rb (dead until cg_init)
  float* xw1 = h;                       // after combine, h region reused
  float* o1  = h + (size_t)N*64;
  float* es  = X;                       // after combine, X region reused
  float* ed  = X + (size_t)N*8;
  float* xw2 = X + (size_t)N*16;
  float* es2 = X + (size_t)N*32;
  float* ed2 = X + (size_t)N*33;
  float* AP  = big1;
  float* T1 = Rb; float* T2 = Pb; float* T3 = big1;

  hipMemsetAsync(deg, 0, (size_t)N*4, stream);
  hipMemsetAsync(cntb, 0, (size_t)N*4, stream);
  hipMemsetAsync(cnti, 0, (size_t)N*4, stream);
  hipMemsetAsync(rs_all, 0, (size_t)(MAXITER+1)*128*4, stream);
  hipMemsetAsync(dn_all, 0, (size_t)MAXITER*128*4, stream);
  hipMemsetAsync(flags, 0, (size_t)(MAXITER+1)*4, stream);

  conv_x<<<(int)(((long)N*IN/4 + 255)/256),256,0,stream>>>(x, xbf, (long)N*IN/4);
  conv_transpose<<<(IN*H+255)/256,256,0,stream>>>(W_in, BtIn, IN, H);
  conv_transpose<<<(H*H+255)/256,256,0,stream>>>(W_sh, Wst, H, H);
  conv_transpose<<<(H*64+255)/256,256,0,stream>>>(W1, W1t, H, 64);

  int gm = (N+63)/64;
  mfma_gemm<IN,H><<<gm,256,0,stream>>>(xbf, BtIn, big1, N);
  ln_sigmoid<<<N,128,0,stream>>>(big1, b_in, ln_g, ln_b, h, hbf);
  mfma_gemm<H,H><<<gm,256,0,stream>>>(hbf, Wst, big1, N);

  count_deg<<<(E+255)/256,256,0,stream>>>(ei, cntb, cnti);
  scan_excl<<<1,1024,0,stream>>>(cntb, N, offb);
  scan_excl<<<1,1024,0,stream>>>(cnti, N, offi);
  hipMemsetAsync(cntb, 0, (size_t)N*4, stream);
  hipMemsetAsync(cnti, 0, (size_t)N*4, stream);
  fill_adj<<<(E+255)/256,256,0,stream>>>(ei, offb, offi, cntb, cnti, adjn, adjeid, adjsrc);

  edge_weights<<<(E+3)/4,256,0,stream>>>(ei, big1, wLp, deg);
  adj_weights<<<(2*E+255)/256,256,0,stream>>>(adjeid, wLp, adjw);

  cg_init<<<1024,256,0,stream>>>(h, X, Rb, Pb, rs_all);
  for (int k=0; k<MAXITER; k++){
    cg_ap<<<(N+3)/4,256,0,stream>>>(flags, k, Pb, offb, adjn, adjw, deg, AP, dn_all+(size_t)k*128);
    cg_xr<<<1024,256,0,stream>>>(flags, k, rs_all+(size_t)k*128, dn_all+(size_t)k*128, Pb, AP, X, Rb, rs_all+(size_t)(k+1)*128);
    cg_p<<<1024,256,0,stream>>>(flags, k, rs_all+(size_t)(k+1)*128, rs_all+(size_t)k*128, Rb, Pb, flags);
  }

  isd_kernel<<<(N+255)/256,256,0,stream>>>(deg, isd);
  tl_apply<<<(N+3)/4,256,0,stream>>>(h,  h,  1.f, 0.f, isd, deg, offb, adjn, adjw, T1);
  tl_apply<<<(N+3)/4,256,0,stream>>>(T1, h,  2.f, 1.f, isd, deg, offb, adjn, adjw, T2);
  tl_apply<<<(N+3)/4,256,0,stream>>>(T2, T1, 2.f, 1.f, isd, deg, offb, adjn, adjw, T3);
  combine_fused<<<1024,256,0,stream>>>(h, X, T1, T2, T3, gamma, asvr, aafm, fusedb);

  mfma_gemm<H,64><<<gm,256,0,stream>>>(fusedb, W1t, xw1, N);
  esed1_kernel<<<(N*8+255)/256,256,0,stream>>>(xw1, a1s, a1d, es, ed);
  gat1<<<(N+3)/4,256,0,stream>>>(offi, adjsrc, es, ed, xw1, b1, o1);
  xw2_kernel<<<(N*16+255)/256,256,0,stream>>>(o1, W2, xw2);
  esed2_kernel<<<(N+255)/256,256,0,stream>>>(xw2, a2s, a2d, es2, ed2);
  gat2<<<(N+3)/4,256,0,stream>>>(offi, adjsrc, es2, ed2, xw2, b2w, (float*)d_out);
}

// Round 3
// 1939.104 us; speedup vs baseline: 1.0968x; 1.0968x over previous
//
#include <hip/hip_runtime.h>

// SVRSheafNet forward on MI355X. FP32 inputs, int32 edge_index, FP32 out.
// Internals fp32; bf16 only at MFMA inputs. Gather kernels unrolled for MLP.

constexpr int N = 50000;
constexpr int E = 512000;
constexpr int IN = 512;
constexpr int H = 128;
constexpr float DT = 0.1f;
constexpr float EPSC = 1e-3f;
constexpr float TOL2 = 1e-8f;
constexpr int MAXITER = 20;

typedef __attribute__((ext_vector_type(8))) short bf16x8;
typedef __attribute__((ext_vector_type(4))) float f32x4;

__device__ inline short f2b(float f){ unsigned u; __builtin_memcpy(&u,&f,4); unsigned r = u + 0x7FFFu + ((u>>16)&1u); return (short)(r>>16); }

// ---------------- fp32 -> bf16 conversions ----------------
__global__ void conv_x(const float* __restrict__ A, short* __restrict__ out, long total4){
  long idx = (long)blockIdx.x*256 + threadIdx.x;
  if (idx < total4){
    float4 v = ((const float4*)A)[idx];
    short4 o; o.x=f2b(v.x); o.y=f2b(v.y); o.z=f2b(v.z); o.w=f2b(v.w);
    ((short4*)out)[idx] = o;
  }
}

// B[K][Nc] fp32 -> Bt[Nc][K] bf16
__global__ void conv_transpose(const float* __restrict__ B, short* __restrict__ Bt, int K, int Nc){
  int id = blockIdx.x*256 + threadIdx.x;
  if (id < K*Nc){ int k = id / Nc, n = id - k*Nc; Bt[(long)n*K + k] = f2b(B[id]); }
}

// ---------------- MFMA GEMM: A[M,K]bf16 @ Bt[TN,K]bf16 -> C[M,TN]f32 ----------------
template<int K, int TN>
__global__ __launch_bounds__(256) void mfma_gemm(const short* __restrict__ A, const short* __restrict__ Bt,
                                                 float* __restrict__ C, int M){
  constexpr int NT = TN/16;
  __shared__ short lA[64][40];
  __shared__ short lB[TN][40];
  int wid = threadIdx.x >> 6, lane = threadIdx.x & 63;
  int ln15 = lane & 15, quad = lane >> 4;
  int m0 = blockIdx.x * 64;
  f32x4 acc[NT];
  #pragma unroll
  for (int t=0;t<NT;t++) acc[t] = (f32x4){0.f,0.f,0.f,0.f};
  for (int k0=0; k0<K; k0+=32){
    {
      int row = threadIdx.x >> 2, q = threadIdx.x & 3;
      int gr = m0 + row;
      uint4 v = {0u,0u,0u,0u};
      if (gr < M) v = *(const uint4*)(A + (long)gr*K + k0 + q*8);
      *(uint4*)&lA[row][q*8] = v;
    }
    if constexpr (TN==128){
      int row = threadIdx.x >> 1, hh = threadIdx.x & 1;
      const uint4* src = (const uint4*)(Bt + (long)row*K + k0 + hh*16);
      *(uint4*)&lB[row][hh*16]   = src[0];
      *(uint4*)&lB[row][hh*16+8] = src[1];
    } else {
      int row = threadIdx.x >> 2, q = threadIdx.x & 3;
      *(uint4*)&lB[row][q*8] = *(const uint4*)(Bt + (long)row*K + k0 + q*8);
    }
    __syncthreads();
    bf16x8 a = *(bf16x8*)&lA[wid*16+ln15][quad*8];
    #pragma unroll
    for (int t=0;t<NT;t++){
      bf16x8 b = *(bf16x8*)&lB[t*16+ln15][quad*8];
      acc[t] = __builtin_amdgcn_mfma_f32_16x16x32_bf16(a, b, acc[t], 0, 0, 0);
    }
    __syncthreads();
  }
  int mr = m0 + wid*16 + quad*4;
  #pragma unroll
  for (int t=0;t<NT;t++){
    #pragma unroll
    for (int r=0;r<4;r++){
      int gr = mr + r;
      if (gr < M) C[(long)gr*TN + t*16 + ln15] = acc[t][r];
    }
  }
}

// ---------------- LayerNorm + sigmoid ----------------
__global__ void ln_sigmoid(const float* __restrict__ pre, const float* __restrict__ b_in,
                           const float* __restrict__ g, const float* __restrict__ bb,
                           float* __restrict__ h, short* __restrict__ hbf){
  int row = blockIdx.x; int t = threadIdx.x; // 128 threads
  float v = pre[(long)row*H + t] + b_in[t];
  __shared__ float sm[2];
  int lane = t & 63, wid = t >> 6;
  float x = v;
  #pragma unroll
  for (int d=32; d; d>>=1) x += __shfl_xor(x, d);
  if (lane==0) sm[wid] = x;
  __syncthreads();
  float mean = (sm[0]+sm[1]) * (1.f/128.f);
  float dv = v - mean;
  __syncthreads();
  x = dv*dv;
  #pragma unroll
  for (int d=32; d; d>>=1) x += __shfl_xor(x, d);
  if (lane==0) sm[wid] = x;
  __syncthreads();
  float var = (sm[0]+sm[1]) * (1.f/128.f);
  float y = dv * rsqrtf(var + 1e-5f) * g[t] + bb[t];
  float hv = 1.f/(1.f+expf(-y));
  h[(long)row*H+t] = hv;
  hbf[(long)row*H+t] = f2b(hv);
}

// ---------------- CSR build ----------------
__global__ void count_deg(const int* __restrict__ ei, int* cntb, int* cnti){
  int e = blockIdx.x*256 + threadIdx.x;
  if (e < E){
    int r = ei[e], c = ei[E+e];
    atomicAdd(&cntb[r],1); atomicAdd(&cntb[c],1); atomicAdd(&cnti[c],1);
  }
}

__global__ __launch_bounds__(1024) void scan_excl(const int* __restrict__ cnt, int n, int* __restrict__ off){
  __shared__ int ws_[16];
  __shared__ int carry;
  if (threadIdx.x==0) carry = 0;
  __syncthreads();
  int lane = threadIdx.x & 63, wid = threadIdx.x >> 6;
  for (int base=0; base<n; base += 1024){
    int i = base + threadIdx.x;
    int v = (i<n) ? cnt[i] : 0;
    int x = v;
    #pragma unroll
    for (int d=1; d<64; d<<=1){ int y = __shfl_up(x, d); if (lane>=d) x += y; }
    if (lane==63) ws_[wid] = x;
    __syncthreads();
    if (threadIdx.x==0){ int acc=0; for (int w=0;w<16;w++){ int t=ws_[w]; ws_[w]=acc; acc+=t; } }
    __syncthreads();
    int excl = carry + ws_[wid] + x - v;
    if (i<n) off[i] = excl;
    __syncthreads();
    if (threadIdx.x==1023) carry = carry + ws_[15] + x;
    __syncthreads();
  }
  if (threadIdx.x==0) off[n] = carry;
}

__global__ void fill_adj(const int* __restrict__ ei, const int* __restrict__ offb, const int* __restrict__ offi,
                         int* curb, int* curi, int* adjn, int* adjeid, int* adjsrc){
  int e = blockIdx.x*256 + threadIdx.x;
  if (e < E){
    int r = ei[e], c = ei[E+e];
    int p = offb[r] + atomicAdd(&curb[r],1); adjn[p]=c; adjeid[p]=e;
    p     = offb[c] + atomicAdd(&curb[c],1); adjn[p]=r; adjeid[p]=e;
    p     = offi[c] + atomicAdd(&curi[c],1); adjsrc[p]=r;
  }
}

__global__ void adj_weights(const int* __restrict__ adjeid, const float* __restrict__ wL, float* __restrict__ adjw){
  int p = blockIdx.x*256 + threadIdx.x;
  if (p < 2*E) adjw[p] = wL[adjeid[p]];
}

// adjw2[p] = adjw[p] * isd[adjn[p]]  (hoists the dependent isd gather out of tl_apply)
__global__ void adj_w_isd(const int* __restrict__ adjn, const float* __restrict__ adjw,
                          const float* __restrict__ isd, float* __restrict__ adjw2){
  int p = blockIdx.x*256 + threadIdx.x;
  if (p < 2*E) adjw2[p] = adjw[p] * isd[adjn[p]];
}

// ---------------- per-edge sheaf weights ----------------
__global__ void edge_weights(const int* __restrict__ ei, const float* __restrict__ hw,
                             float* __restrict__ wL, float* __restrict__ deg){
  int wid = threadIdx.x >> 6, lane = threadIdx.x & 63;
  int e = blockIdx.x*4 + wid;
  if (e >= E) return;
  int r = ei[e], c = ei[E+e];
  const float2* Hc = (const float2*)hw;
  float2 fr = Hc[(long)r*64 + lane];
  float2 fc = Hc[(long)c*64 + lane];
  float dx = fr.x-fc.x, dy = fr.y-fc.y;
  float sd = dx*dx + dy*dy;
  float sr = fr.x*fr.x + fr.y*fr.y;
  #pragma unroll
  for (int d=32; d; d>>=1){ sd += __shfl_xor(sd,d); sr += __shfl_xor(sr,d); }
  if (lane==0){
    float C  = sd * (1.0f/128.0f);
    float P0 = fminf(fmaxf(expf(-C*(1.0f/EPSC)), 1e-3f), 1.0f);
    float Ps = fminf(fmaxf(expf(logf(P0+1e-12f) - C*(1.0f/EPSC)), 1e-3f), 1.0f);
    float w  = 0.7f*P0 + 0.3f*Ps;
    float wl = w*w*sr*(1.0f/128.0f);
    wL[e] = wl;
    atomicAdd(&deg[r], wl);
    atomicAdd(&deg[c], wl);
  }
}

// ---------------- CG ----------------
__global__ void cg_init(const float* __restrict__ h, float* __restrict__ X, float* __restrict__ R,
                        float* __restrict__ P, float* __restrict__ rs0){
  __shared__ float cols[128];
  if (threadIdx.x < 128) cols[threadIdx.x] = 0.f;
  __syncthreads();
  int total = N*32;
  float4 z = {0,0,0,0};
  for (int idx = blockIdx.x*blockDim.x + threadIdx.x; idx < total; idx += gridDim.x*blockDim.x){
    float4 hv = ((const float4*)h)[idx];
    ((float4*)X)[idx] = z; ((float4*)R)[idx] = hv; ((float4*)P)[idx] = hv;
    int c4 = (idx & 31)*4;
    atomicAdd(&cols[c4+0], hv.x*hv.x);
    atomicAdd(&cols[c4+1], hv.y*hv.y);
    atomicAdd(&cols[c4+2], hv.z*hv.z);
    atomicAdd(&cols[c4+3], hv.w*hv.w);
  }
  __syncthreads();
  if (threadIdx.x < 128){ float v = cols[threadIdx.x]; if (v != 0.f) atomicAdd(&rs0[threadIdx.x], v); }
}

__global__ void cg_ap(const int* __restrict__ flags, int k, const float* __restrict__ P,
                      const int* __restrict__ offb, const int* __restrict__ adjn, const float* __restrict__ adjw,
                      const float* __restrict__ deg, float* __restrict__ AP, float* __restrict__ dn){
  if (flags[k]) return;
  __shared__ float cols[128];
  if (threadIdx.x < 128) cols[threadIdx.x] = 0.f;
  __syncthreads();
  int wid = threadIdx.x >> 6, lane = threadIdx.x & 63;
  int node = blockIdx.x*4 + wid;
  if (node < N){
    const float2* Pc = (const float2*)P;
    float2 acc = {0.f,0.f};
    int p0 = offb[node], p1 = offb[node+1];
    int p = p0;
    for (; p+8 <= p1; p += 8){
      int jj[8]; float ww[8];
      #pragma unroll
      for (int t=0;t<8;t++){ jj[t] = adjn[p+t]; ww[t] = adjw[p+t]; }
      float2 vv[8];
      #pragma unroll
      for (int t=0;t<8;t++) vv[t] = Pc[(long)jj[t]*64 + lane];
      #pragma unroll
      for (int t=0;t<8;t++){ acc.x += ww[t]*vv[t].x; acc.y += ww[t]*vv[t].y; }
    }
    for (; p<p1; p++){
      int j = adjn[p]; float w = adjw[p];
      float2 pj = Pc[(long)j*64 + lane];
      acc.x += w*pj.x; acc.y += w*pj.y;
    }
    float dg = deg[node];
    float2 pi = Pc[(long)node*64 + lane];
    float2 ap;
    ap.x = pi.x + DT*(dg*pi.x - acc.x);
    ap.y = pi.y + DT*(dg*pi.y - acc.y);
    ((float2*)AP)[(long)node*64 + lane] = ap;
    atomicAdd(&cols[lane*2],   pi.x*ap.x);
    atomicAdd(&cols[lane*2+1], pi.y*ap.y);
  }
  __syncthreads();
  if (threadIdx.x < 128){ float v = cols[threadIdx.x]; if (v != 0.f) atomicAdd(&dn[threadIdx.x], v); }
}

__global__ void cg_xr(const int* __restrict__ flags, int k, const float* __restrict__ rs, const float* __restrict__ dn,
                      const float* __restrict__ P, const float* __restrict__ AP,
                      float* __restrict__ X, float* __restrict__ R, float* __restrict__ rsn){
  if (flags[k]) return;
  __shared__ float cols[128];
  if (threadIdx.x < 128) cols[threadIdx.x] = 0.f;
  __syncthreads();
  int total = N*32;
  for (int idx = blockIdx.x*blockDim.x + threadIdx.x; idx < total; idx += gridDim.x*blockDim.x){
    int c4 = (idx & 31)*4;
    float a0 = rs[c4+0]/(dn[c4+0]+1e-16f);
    float a1 = rs[c4+1]/(dn[c4+1]+1e-16f);
    float a2 = rs[c4+2]/(dn[c4+2]+1e-16f);
    float a3 = rs[c4+3]/(dn[c4+3]+1e-16f);
    float4 p  = ((const float4*)P)[idx];
    float4 ap = ((const float4*)AP)[idx];
    float4 x  = ((float4*)X)[idx];
    float4 r  = ((float4*)R)[idx];
    x.x += a0*p.x; x.y += a1*p.y; x.z += a2*p.z; x.w += a3*p.w;
    r.x -= a0*ap.x; r.y -= a1*ap.y; r.z -= a2*ap.z; r.w -= a3*ap.w;
    ((float4*)X)[idx] = x; ((float4*)R)[idx] = r;
    atomicAdd(&cols[c4+0], r.x*r.x);
    atomicAdd(&cols[c4+1], r.y*r.y);
    atomicAdd(&cols[c4+2], r.z*r.z);
    atomicAdd(&cols[c4+3], r.w*r.w);
  }
  __syncthreads();
  if (threadIdx.x < 128){ float v = cols[threadIdx.x]; if (v != 0.f) atomicAdd(&rsn[threadIdx.x], v); }
}

__global__ void cg_p(const int* __restrict__ flags, int k, const float* __restrict__ rsn, const float* __restrict__ rsp,
                     const float* __restrict__ R, float* __restrict__ P, int* __restrict__ flags_w){
  if (flags[k]){ if (threadIdx.x==0) flags_w[k+1] = 1; return; }
  __shared__ float red[4];
  __shared__ int done_s;
  float v = (threadIdx.x < 128) ? rsn[threadIdx.x] : -1.f;
  #pragma unroll
  for (int d=32; d; d>>=1) v = fmaxf(v, __shfl_xor(v, d));
  if ((threadIdx.x & 63)==0) red[threadIdx.x>>6] = v;
  __syncthreads();
  if (threadIdx.x==0){
    float m = fmaxf(fmaxf(red[0],red[1]), fmaxf(red[2],red[3]));
    done_s = (m < TOL2) ? 1 : 0;
  }
  __syncthreads();
  if (done_s){ if (threadIdx.x==0) flags_w[k+1] = 1; return; }
  int total = N*32;
  for (int idx = blockIdx.x*blockDim.x + threadIdx.x; idx < total; idx += gridDim.x*blockDim.x){
    int c4 = (idx & 31)*4;
    float b0 = rsn[c4+0]/(rsp[c4+0]+1e-16f);
    float b1v = rsn[c4+1]/(rsp[c4+1]+1e-16f);
    float b2v = rsn[c4+2]/(rsp[c4+2]+1e-16f);
    float b3 = rsn[c4+3]/(rsp[c4+3]+1e-16f);
    float4 r = ((const float4*)R)[idx];
    float4 p = ((float4*)P)[idx];
    p.x = r.x + b0*p.x; p.y = r.y + b1v*p.y; p.z = r.z + b2v*p.z; p.w = r.w + b3*p.w;
    ((float4*)P)[idx] = p;
  }
}

// ---------------- AFM ----------------
__global__ void isd_kernel(const float* __restrict__ deg, float* __restrict__ isd){
  int i = blockIdx.x*256 + threadIdx.x;
  if (i < N) isd[i] = sqrtf(1.f / fmaxf(deg[i], 1e-8f));
}

// out = alpha*tildeL(Min) - beta*Mprev, with adjw2[p] = adjw[p]*isd[adjn[p]]
__global__ void tl_apply(const float* __restrict__ Min, const float* __restrict__ Mprev, float alpha, float beta,
                         const float* __restrict__ isd, const float* __restrict__ deg, const int* __restrict__ offb,
                         const int* __restrict__ adjn, const float* __restrict__ adjw2, float* __restrict__ out){
  int wid = threadIdx.x >> 6, lane = threadIdx.x & 63;
  int node = blockIdx.x*4 + wid;
  if (node >= N) return;
  const float2* Mc = (const float2*)Min;
  const float2* Pv = (const float2*)Mprev;
  float2 acc = {0.f,0.f};
  int p0 = offb[node], p1 = offb[node+1];
  int p = p0;
  for (; p+8 <= p1; p += 8){
    int jj[8]; float ww[8];
    #pragma unroll
    for (int t=0;t<8;t++){ jj[t] = adjn[p+t]; ww[t] = adjw2[p+t]; }
    float2 vv[8];
    #pragma unroll
    for (int t=0;t<8;t++) vv[t] = Mc[(long)jj[t]*64 + lane];
    #pragma unroll
    for (int t=0;t<8;t++){ acc.x += ww[t]*vv[t].x; acc.y += ww[t]*vv[t].y; }
  }
  for (; p<p1; p++){
    int j = adjn[p]; float w = adjw2[p];
    float2 mj = Mc[(long)j*64 + lane];
    acc.x += w*mj.x; acc.y += w*mj.y;
  }
  float ii = isd[node]; float dg = deg[node];
  float2 mi = Mc[(long)node*64 + lane];
  float2 pv = Pv[(long)node*64 + lane];
  float2 o;
  o.x = alpha*(mi.x + ii*(dg*ii*mi.x - acc.x)) - beta*pv.x;
  o.y = alpha*(mi.y + ii*(dg*ii*mi.y - acc.y)) - beta*pv.y;
  ((float2*)out)[(long)node*64 + lane] = o;
}

__global__ void combine_fused(const float* __restrict__ h, const float* __restrict__ X,
                              const float* __restrict__ T1, const float* __restrict__ T2, const float* __restrict__ T3,
                              const float* __restrict__ gamma, const float* __restrict__ asvr, const float* __restrict__ aafm,
                              short* __restrict__ fusedb){
  float g0=gamma[0], g1=gamma[1], g2=gamma[2], g3=gamma[3];
  float mg = fmaxf(fmaxf(g0,g1), fmaxf(g2,g3));
  float e0=expf(g0-mg), e1=expf(g1-mg), e2=expf(g2-mg), e3=expf(g3-mg);
  float s = e0+e1+e2+e3;
  float a0=e0/s, a1=e1/s, a2=e2/s, a3=e3/s;
  float s1 = 1.f/(1.f+expf(-asvr[0]));
  float s2 = 1.f/(1.f+expf(-aafm[0]));
  int total = N*H;
  for (int i = blockIdx.x*blockDim.x + threadIdx.x; i < total; i += gridDim.x*blockDim.x){
    float hv = h[i];
    float v = hv + s1*X[i] + s2*(a0*hv + a1*T1[i] + a2*T2[i] + a3*T3[i]);
    fusedb[i] = f2b(v);
  }
}

// ---------------- GAT ----------------
__global__ void esed1_kernel(const float* __restrict__ xw1, const float* __restrict__ a1s, const float* __restrict__ a1d,
                             float* __restrict__ es, float* __restrict__ ed){
  int id = blockIdx.x*256 + threadIdx.x;
  if (id < N*8){
    int n = id >> 3, hd = id & 7;
    const float* xr = xw1 + (long)n*64 + hd*8;
    float s=0.f, d=0.f;
    #pragma unroll
    for (int c=0;c<8;c++){ float v = xr[c]; s += v*a1s[hd*8+c]; d += v*a1d[hd*8+c]; }
    es[id]=s; ed[id]=d;
  }
}

// single-pass online-softmax GAT layer 1 (8 heads x 8 ch), wave per dst node
__global__ void gat1(const int* __restrict__ offi, const int* __restrict__ adjsrc,
                     const float* __restrict__ es, const float* __restrict__ ed,
                     const float* __restrict__ xw1, const float* __restrict__ b1, float* __restrict__ o1){
  int wid = threadIdx.x >> 6, lane = threadIdx.x & 63;
  int d = blockIdx.x*4 + wid;
  if (d >= N) return;
  int hd = lane >> 3;
  float edd = ed[d*8+hd];
  float esd = es[d*8+hd];
  auto lk = [](float x){ return x >= 0.f ? x : 0.2f*x; };
  // self-loop as initial state
  float m = lk(esd+edd);
  float den = 1.f;
  float num = xw1[(long)d*64 + lane];
  int p0 = offi[d], p1 = offi[d+1];
  int p = p0;
  for (; p+4 <= p1; p += 4){
    int ss[4];
    #pragma unroll
    for (int t=0;t<4;t++) ss[t] = adjsrc[p+t];
    float ee[4], vv[4];
    #pragma unroll
    for (int t=0;t<4;t++){ ee[t] = es[ss[t]*8+hd]; vv[t] = xw1[(long)ss[t]*64 + lane]; }
    #pragma unroll
    for (int t=0;t<4;t++){
      float e = lk(ee[t]+edd);
      float mn = fmaxf(m, e);
      float sc = expf(m-mn), ex = expf(e-mn);
      den = den*sc + ex;
      num = num*sc + ex*vv[t];
      m = mn;
    }
  }
  for (; p<p1; p++){
    int s = adjsrc[p];
    float e = lk(es[s*8+hd]+edd);
    float v = xw1[(long)s*64 + lane];
    float mn = fmaxf(m, e);
    float sc = expf(m-mn), ex = expf(e-mn);
    den = den*sc + ex;
    num = num*sc + ex*v;
    m = mn;
  }
  float o = num/(den+1e-16f) + b1[lane];
  o1[(long)d*64+lane] = o > 0.f ? o : expm1f(o);
}

__global__ void xw2_kernel(const float* __restrict__ o1, const float* __restrict__ W2, float* __restrict__ xw2){
  __shared__ float w2s[64*16];
  for (int i=threadIdx.x; i<64*16; i+=256) w2s[i] = W2[i];
  __syncthreads();
  int id = blockIdx.x*256 + threadIdx.x;
  if (id < N*16){
    int n = id >> 4, c = id & 15;
    const float* orow = o1 + (long)n*64;
    float acc = 0.f;
    #pragma unroll
    for (int kk=0; kk<64; kk++) acc += orow[kk]*w2s[kk*16+c];
    xw2[id] = acc;
  }
}

__global__ void esed2_kernel(const float* __restrict__ xw2, const float* __restrict__ a2s, const float* __restrict__ a2d,
                             float* __restrict__ es2, float* __restrict__ ed2){
  int n = blockIdx.x*256 + threadIdx.x;
  if (n < N){
    float s=0.f, d=0.f;
    #pragma unroll
    for (int c=0;c<16;c++){ float v = xw2[(long)n*16+c]; s += v*a2s[c]; d += v*a2d[c]; }
    es2[n]=s; ed2[n]=d;
  }
}

// single-pass online-softmax GAT layer 2 (1 head, 16 ch)
__global__ void gat2(const int* __restrict__ offi, const int* __restrict__ adjsrc,
                     const float* __restrict__ es2, const float* __restrict__ ed2,
                     const float* __restrict__ xw2, const float* __restrict__ b2w, float* __restrict__ out){
  int wid = threadIdx.x >> 6, lane = threadIdx.x & 63;
  int d = blockIdx.x*4 + wid;
  if (d >= N) return;
  auto lk = [](float x){ return x >= 0.f ? x : 0.2f*x; };
  float edd = ed2[d];
  float m = lk(es2[d]+edd);
  float den = 1.f;
  float num = (lane<16) ? xw2[(long)d*16+lane] : 0.f;
  int p0 = offi[d], p1 = offi[d+1];
  int p = p0;
  for (; p+4 <= p1; p += 4){
    int ss[4];
    #pragma unroll
    for (int t=0;t<4;t++) ss[t] = adjsrc[p+t];
    float ee[4], vv[4];
    #pragma unroll
    for (int t=0;t<4;t++){ ee[t] = es2[ss[t]]; vv[t] = (lane<16) ? xw2[(long)ss[t]*16+lane] : 0.f; }
    #pragma unroll
    for (int t=0;t<4;t++){
      float e = lk(ee[t]+edd);
      float mn = fmaxf(m, e);
      float sc = expf(m-mn), ex = expf(e-mn);
      den = den*sc + ex;
      num = num*sc + ex*vv[t];
      m = mn;
    }
  }
  for (; p<p1; p++){
    int s = adjsrc[p];
    float e = lk(es2[s]+edd);
    float v = (lane<16) ? xw2[(long)s*16+lane] : 0.f;
    float mn = fmaxf(m, e);
    float sc = expf(m-mn), ex = expf(e-mn);
    den = den*sc + ex;
    num = num*sc + ex*v;
    m = mn;
  }
  if (lane<16) out[(long)d*16+lane] = num/(den+1e-16f) + b2w[lane];
}

// ---------------- host ----------------
extern "C" void kernel_launch(void* const* d_in, const int* in_sizes, int n_in,
                              void* d_out, int out_size, void* d_ws, size_t ws_size,
                              hipStream_t stream){
  const float* x     = (const float*)d_in[0];
  const int*   ei    = (const int*)  d_in[1];
  const float* W_in  = (const float*)d_in[2];
  const float* b_in  = (const float*)d_in[3];
  const float* ln_g  = (const float*)d_in[4];
  const float* ln_b  = (const float*)d_in[5];
  const float* W_sh  = (const float*)d_in[6];
  const float* gamma = (const float*)d_in[7];
  const float* asvr  = (const float*)d_in[8];
  const float* aafm  = (const float*)d_in[9];
  const float* W1    = (const float*)d_in[10];
  const float* a1s   = (const float*)d_in[11];
  const float* a1d   = (const float*)d_in[12];
  const float* b1    = (const float*)d_in[13];
  const float* W2    = (const float*)d_in[14];
  const float* a2s   = (const float*)d_in[15];
  const float* a2d   = (const float*)d_in[16];
  const float* b2w   = (const float*)d_in[17];

  char* ws = (char*)d_ws;
  size_t off = 0;
  auto alloc = [&](size_t bytes)->char*{ char* p = ws + off; off = (off + bytes + 255) & ~(size_t)255; return p; };
  float* h    = (float*)alloc((size_t)N*H*4);
  float* big1 = (float*)alloc((size_t)N*H*4); // preLN -> hw -> AP -> T3
  float* X    = (float*)alloc((size_t)N*H*4);
  float* Rb   = (float*)alloc((size_t)N*H*4); // R -> T1
  float* Pb   = (float*)alloc((size_t)N*H*4); // P -> T2
  short* hbf  = (short*)alloc((size_t)N*H*2);
  short* fusedb = (short*)alloc((size_t)N*H*2);
  float* wLp  = (float*)alloc((size_t)E*4);
  float* deg  = (float*)alloc((size_t)N*4);
  float* isd  = (float*)alloc((size_t)N*4);
  int* cntb   = (int*)alloc((size_t)N*4);
  int* cnti   = (int*)alloc((size_t)N*4);
  int* offb   = (int*)alloc((size_t)(N+1)*4);
  int* offi   = (int*)alloc((size_t)(N+1)*4);
  int* adjn   = (int*)alloc((size_t)2*E*4);
  int* adjeid = (int*)alloc((size_t)2*E*4);
  float* adjw = (float*)alloc((size_t)2*E*4);
  int* adjsrc = (int*)alloc((size_t)E*4);
  short* BtIn = (short*)alloc((size_t)IN*H*2);
  short* Wst  = (short*)alloc((size_t)H*H*2);
  short* W1t  = (short*)alloc((size_t)H*64*2);
  float* rs_all = (float*)alloc((size_t)(MAXITER+1)*128*4);
  float* dn_all = (float*)alloc((size_t)MAXITER*128*4);
  int* flags  = (int*)alloc((size_t)(MAXITER+1)*4);

  // aliases (regions dead by the time these are written)
  short* xbf = (short*)X;               // N*IN bf16 = 51.2MB, spans X+Rb (dead until cg_init)
  float* adjw2 = (float*)adjeid;        // adjeid dead after adj_weights
  float* xw1 = h;                       // after combine, h region reused
  float* o1  = h + (size_t)N*64;
  float* es  = X;                       // after combine, X region reused
  float* ed  = X + (size_t)N*8;
  float* xw2 = X + (size_t)N*16;
  float* es2 = X + (size_t)N*32;
  float* ed2 = X + (size_t)N*33;
  float* AP  = big1;
  float* T1 = Rb; float* T2 = Pb; float* T3 = big1;

  hipMemsetAsync(deg, 0, (size_t)N*4, stream);
  hipMemsetAsync(cntb, 0, (size_t)N*4, stream);
  hipMemsetAsync(cnti, 0, (size_t)N*4, stream);
  hipMemsetAsync(rs_all, 0, (size_t)(MAXITER+1)*128*4, stream);
  hipMemsetAsync(dn_all, 0, (size_t)MAXITER*128*4, stream);
  hipMemsetAsync(flags, 0, (size_t)(MAXITER+1)*4, stream);

  conv_x<<<(int)(((long)N*IN/4 + 255)/256),256,0,stream>>>(x, xbf, (long)N*IN/4);
  conv_transpose<<<(IN*H+255)/256,256,0,stream>>>(W_in, BtIn, IN, H);
  conv_transpose<<<(H*H+255)/256,256,0,stream>>>(W_sh, Wst, H, H);
  conv_transpose<<<(H*64+255)/256,256,0,stream>>>(W1, W1t, H, 64);

  int gm = (N+63)/64;
  mfma_gemm<IN,H><<<gm,256,0,stream>>>(xbf, BtIn, big1, N);
  ln_sigmoid<<<N,128,0,stream>>>(big1, b_in, ln_g, ln_b, h, hbf);
  mfma_gemm<H,H><<<gm,256,0,stream>>>(hbf, Wst, big1, N);

  count_deg<<<(E+255)/256,256,0,stream>>>(ei, cntb, cnti);
  scan_excl<<<1,1024,0,stream>>>(cntb, N, offb);
  scan_excl<<<1,1024,0,stream>>>(cnti, N, offi);
  hipMemsetAsync(cntb, 0, (size_t)N*4, stream);
  hipMemsetAsync(cnti, 0, (size_t)N*4, stream);
  fill_adj<<<(E+255)/256,256,0,stream>>>(ei, offb, offi, cntb, cnti, adjn, adjeid, adjsrc);

  edge_weights<<<(E+3)/4,256,0,stream>>>(ei, big1, wLp, deg);
  adj_weights<<<(2*E+255)/256,256,0,stream>>>(adjeid, wLp, adjw);

  cg_init<<<1024,256,0,stream>>>(h, X, Rb, Pb, rs_all);
  for (int k=0; k<MAXITER; k++){
    cg_ap<<<(N+3)/4,256,0,stream>>>(flags, k, Pb, offb, adjn, adjw, deg, AP, dn_all+(size_t)k*128);
    cg_xr<<<1024,256,0,stream>>>(flags, k, rs_all+(size_t)k*128, dn_all+(size_t)k*128, Pb, AP, X, Rb, rs_all+(size_t)(k+1)*128);
    cg_p<<<1024,256,0,stream>>>(flags, k, rs_all+(size_t)(k+1)*128, rs_all+(size_t)k*128, Rb, Pb, flags);
  }

  isd_kernel<<<(N+255)/256,256,0,stream>>>(deg, isd);
  adj_w_isd<<<(2*E+255)/256,256,0,stream>>>(adjn, adjw, isd, adjw2);
  tl_apply<<<(N+3)/4,256,0,stream>>>(h,  h,  1.f, 0.f, isd, deg, offb, adjn, adjw2, T1);
  tl_apply<<<(N+3)/4,256,0,stream>>>(T1, h,  2.f, 1.f, isd, deg, offb, adjn, adjw2, T2);
  tl_apply<<<(N+3)/4,256,0,stream>>>(T2, T1, 2.f, 1.f, isd, deg, offb, adjn, adjw2, T3);
  combine_fused<<<1024,256,0,stream>>>(h, X, T1, T2, T3, gamma, asvr, aafm, fusedb);

  mfma_gemm<H,64><<<gm,256,0,stream>>>(fusedb, W1t, xw1, N);
  esed1_kernel<<<(N*8+255)/256,256,0,stream>>>(xw1, a1s, a1d, es, ed);
  gat1<<<(N+3)/4,256,0,stream>>>(offi, adjsrc, es, ed, xw1, b1, o1);
  xw2_kernel<<<(N*16+255)/256,256,0,stream>>>(o1, W2, xw2);
  esed2_kernel<<<(N+255)/256,256,0,stream>>>(xw2, a2s, a2d, es2, ed2);
  gat2<<<(N+3)/4,256,0,stream>>>(offi, adjsrc, es2, ed2, xw2, b2w, (float*)d_out);
}

// Round 4
// 1846.463 us; speedup vs baseline: 1.1518x; 1.0502x over previous
//
#include <hip/hip_runtime.h>

// SVRSheafNet forward on MI355X. FP32 inputs, int32 edge_index, FP32 out.
// Random node-row gathers are the bottleneck (per-CU miss-concurrency bound),
// so all gathered tables are stored as bf16 (half the cache lines per edge).
// Local/self rows and all accumulation stay fp32.

constexpr int N = 50000;
constexpr int E = 512000;
constexpr int IN = 512;
constexpr int H = 128;
constexpr float DT = 0.1f;
constexpr float EPSC = 1e-3f;
constexpr float TOL2 = 1e-8f;
constexpr int MAXITER = 20;

typedef __attribute__((ext_vector_type(8))) short bf16x8;
typedef __attribute__((ext_vector_type(4))) float f32x4;

__device__ inline short f2b(float f){ unsigned u; __builtin_memcpy(&u,&f,4); unsigned r = u + 0x7FFFu + ((u>>16)&1u); return (short)(r>>16); }
__device__ inline float2 ub2f2(unsigned u){
  unsigned lo = u << 16, hi = u & 0xFFFF0000u;
  float a,b; __builtin_memcpy(&a,&lo,4); __builtin_memcpy(&b,&hi,4);
  return (float2){a,b};
}
__device__ inline float ub2f(unsigned short s){
  unsigned u = ((unsigned)s) << 16; float f; __builtin_memcpy(&f,&u,4); return f;
}
__device__ inline unsigned pack2(float x, float y){
  return (unsigned)(unsigned short)f2b(x) | ((unsigned)(unsigned short)f2b(y) << 16);
}

// ---------------- fp32 -> bf16 conversions ----------------
__global__ void conv_x(const float* __restrict__ A, short* __restrict__ out, long total4){
  long idx = (long)blockIdx.x*256 + threadIdx.x;
  if (idx < total4){
    float4 v = ((const float4*)A)[idx];
    short4 o; o.x=f2b(v.x); o.y=f2b(v.y); o.z=f2b(v.z); o.w=f2b(v.w);
    ((short4*)out)[idx] = o;
  }
}

// B[K][Nc] fp32 -> Bt[Nc][K] bf16
__global__ void conv_transpose(const float* __restrict__ B, short* __restrict__ Bt, int K, int Nc){
  int id = blockIdx.x*256 + threadIdx.x;
  if (id < K*Nc){ int k = id / Nc, n = id - k*Nc; Bt[(long)n*K + k] = f2b(B[id]); }
}

// ---------------- MFMA GEMM: A[M,K]bf16 @ Bt[TN,K]bf16 -> C[M,TN]f32 (+ optional bf16 copy) ----------------
template<int K, int TN, bool WB16>
__global__ __launch_bounds__(256) void mfma_gemm(const short* __restrict__ A, const short* __restrict__ Bt,
                                                 float* __restrict__ C, short* __restrict__ Cb, int M){
  constexpr int NT = TN/16;
  __shared__ short lA[64][40];
  __shared__ short lB[TN][40];
  int wid = threadIdx.x >> 6, lane = threadIdx.x & 63;
  int ln15 = lane & 15, quad = lane >> 4;
  int m0 = blockIdx.x * 64;
  f32x4 acc[NT];
  #pragma unroll
  for (int t=0;t<NT;t++) acc[t] = (f32x4){0.f,0.f,0.f,0.f};
  for (int k0=0; k0<K; k0+=32){
    {
      int row = threadIdx.x >> 2, q = threadIdx.x & 3;
      int gr = m0 + row;
      uint4 v = {0u,0u,0u,0u};
      if (gr < M) v = *(const uint4*)(A + (long)gr*K + k0 + q*8);
      *(uint4*)&lA[row][q*8] = v;
    }
    if constexpr (TN==128){
      int row = threadIdx.x >> 1, hh = threadIdx.x & 1;
      const uint4* src = (const uint4*)(Bt + (long)row*K + k0 + hh*16);
      *(uint4*)&lB[row][hh*16]   = src[0];
      *(uint4*)&lB[row][hh*16+8] = src[1];
    } else {
      int row = threadIdx.x >> 2, q = threadIdx.x & 3;
      *(uint4*)&lB[row][q*8] = *(const uint4*)(Bt + (long)row*K + k0 + q*8);
    }
    __syncthreads();
    bf16x8 a = *(bf16x8*)&lA[wid*16+ln15][quad*8];
    #pragma unroll
    for (int t=0;t<NT;t++){
      bf16x8 b = *(bf16x8*)&lB[t*16+ln15][quad*8];
      acc[t] = __builtin_amdgcn_mfma_f32_16x16x32_bf16(a, b, acc[t], 0, 0, 0);
    }
    __syncthreads();
  }
  int mr = m0 + wid*16 + quad*4;
  #pragma unroll
  for (int t=0;t<NT;t++){
    #pragma unroll
    for (int r=0;r<4;r++){
      int gr = mr + r;
      if (gr < M){
        C[(long)gr*TN + t*16 + ln15] = acc[t][r];
        if constexpr (WB16) Cb[(long)gr*TN + t*16 + ln15] = f2b(acc[t][r]);
      }
    }
  }
}

// ---------------- LayerNorm + sigmoid ----------------
__global__ void ln_sigmoid(const float* __restrict__ pre, const float* __restrict__ b_in,
                           const float* __restrict__ g, const float* __restrict__ bb,
                           float* __restrict__ h, short* __restrict__ hbf){
  int row = blockIdx.x; int t = threadIdx.x; // 128 threads
  float v = pre[(long)row*H + t] + b_in[t];
  __shared__ float sm[2];
  int lane = t & 63, wid = t >> 6;
  float x = v;
  #pragma unroll
  for (int d=32; d; d>>=1) x += __shfl_xor(x, d);
  if (lane==0) sm[wid] = x;
  __syncthreads();
  float mean = (sm[0]+sm[1]) * (1.f/128.f);
  float dv = v - mean;
  __syncthreads();
  x = dv*dv;
  #pragma unroll
  for (int d=32; d; d>>=1) x += __shfl_xor(x, d);
  if (lane==0) sm[wid] = x;
  __syncthreads();
  float var = (sm[0]+sm[1]) * (1.f/128.f);
  float y = dv * rsqrtf(var + 1e-5f) * g[t] + bb[t];
  float hv = 1.f/(1.f+expf(-y));
  h[(long)row*H+t] = hv;
  hbf[(long)row*H+t] = f2b(hv);
}

// ---------------- CSR build ----------------
__global__ void count_deg(const int* __restrict__ ei, int* cntb, int* cnti){
  int e = blockIdx.x*256 + threadIdx.x;
  if (e < E){
    int r = ei[e], c = ei[E+e];
    atomicAdd(&cntb[r],1); atomicAdd(&cntb[c],1); atomicAdd(&cnti[c],1);
  }
}

__global__ __launch_bounds__(1024) void scan_excl(const int* __restrict__ cnt, int n, int* __restrict__ off){
  __shared__ int ws_[16];
  __shared__ int carry;
  if (threadIdx.x==0) carry = 0;
  __syncthreads();
  int lane = threadIdx.x & 63, wid = threadIdx.x >> 6;
  for (int base=0; base<n; base += 1024){
    int i = base + threadIdx.x;
    int v = (i<n) ? cnt[i] : 0;
    int x = v;
    #pragma unroll
    for (int d=1; d<64; d<<=1){ int y = __shfl_up(x, d); if (lane>=d) x += y; }
    if (lane==63) ws_[wid] = x;
    __syncthreads();
    if (threadIdx.x==0){ int acc=0; for (int w=0;w<16;w++){ int t=ws_[w]; ws_[w]=acc; acc+=t; } }
    __syncthreads();
    int excl = carry + ws_[wid] + x - v;
    if (i<n) off[i] = excl;
    __syncthreads();
    if (threadIdx.x==1023) carry = carry + ws_[15] + x;
    __syncthreads();
  }
  if (threadIdx.x==0) off[n] = carry;
}

__global__ void fill_adj(const int* __restrict__ ei, const int* __restrict__ offb, const int* __restrict__ offi,
                         int* curb, int* curi, int* adjn, int* adjeid, int* adjsrc){
  int e = blockIdx.x*256 + threadIdx.x;
  if (e < E){
    int r = ei[e], c = ei[E+e];
    int p = offb[r] + atomicAdd(&curb[r],1); adjn[p]=c; adjeid[p]=e;
    p     = offb[c] + atomicAdd(&curb[c],1); adjn[p]=r; adjeid[p]=e;
    p     = offi[c] + atomicAdd(&curi[c],1); adjsrc[p]=r;
  }
}

__global__ void adj_weights(const int* __restrict__ adjeid, const float* __restrict__ wL, float* __restrict__ adjw){
  int p = blockIdx.x*256 + threadIdx.x;
  if (p < 2*E) adjw[p] = wL[adjeid[p]];
}

// adjw2[p] = adjw[p] * isd[adjn[p]]
__global__ void adj_w_isd(const int* __restrict__ adjn, const float* __restrict__ adjw,
                          const float* __restrict__ isd, float* __restrict__ adjw2){
  int p = blockIdx.x*256 + threadIdx.x;
  if (p < 2*E) adjw2[p] = adjw[p] * isd[adjn[p]];
}

// ---------------- per-edge sheaf weights (bf16 hw rows) ----------------
__global__ void edge_weights(const int* __restrict__ ei, const unsigned* __restrict__ hwb,
                             float* __restrict__ wL, float* __restrict__ deg){
  int wid = threadIdx.x >> 6, lane = threadIdx.x & 63;
  int e = blockIdx.x*4 + wid;
  if (e >= E) return;
  int r = ei[e], c = ei[E+e];
  float2 fr = ub2f2(hwb[(long)r*64 + lane]);
  float2 fc = ub2f2(hwb[(long)c*64 + lane]);
  float dx = fr.x-fc.x, dy = fr.y-fc.y;
  float sd = dx*dx + dy*dy;
  float sr = fr.x*fr.x + fr.y*fr.y;
  #pragma unroll
  for (int d=32; d; d>>=1){ sd += __shfl_xor(sd,d); sr += __shfl_xor(sr,d); }
  if (lane==0){
    float C  = sd * (1.0f/128.0f);
    float P0 = fminf(fmaxf(expf(-C*(1.0f/EPSC)), 1e-3f), 1.0f);
    float Ps = fminf(fmaxf(expf(logf(P0+1e-12f) - C*(1.0f/EPSC)), 1e-3f), 1.0f);
    float w  = 0.7f*P0 + 0.3f*Ps;
    float wl = w*w*sr*(1.0f/128.0f);
    wL[e] = wl;
    atomicAdd(&deg[r], wl);
    atomicAdd(&deg[c], wl);
  }
}

// ---------------- CG ----------------
__global__ void cg_init(const float* __restrict__ h, float* __restrict__ X, float* __restrict__ R,
                        float* __restrict__ P, short* __restrict__ Pbf, float* __restrict__ rs0){
  __shared__ float cols[128];
  if (threadIdx.x < 128) cols[threadIdx.x] = 0.f;
  __syncthreads();
  int total = N*32;
  float4 z = {0,0,0,0};
  for (int idx = blockIdx.x*blockDim.x + threadIdx.x; idx < total; idx += gridDim.x*blockDim.x){
    float4 hv = ((const float4*)h)[idx];
    ((float4*)X)[idx] = z; ((float4*)R)[idx] = hv; ((float4*)P)[idx] = hv;
    short4 pb; pb.x=f2b(hv.x); pb.y=f2b(hv.y); pb.z=f2b(hv.z); pb.w=f2b(hv.w);
    ((short4*)Pbf)[idx] = pb;
    int c4 = (idx & 31)*4;
    atomicAdd(&cols[c4+0], hv.x*hv.x);
    atomicAdd(&cols[c4+1], hv.y*hv.y);
    atomicAdd(&cols[c4+2], hv.z*hv.z);
    atomicAdd(&cols[c4+3], hv.w*hv.w);
  }
  __syncthreads();
  if (threadIdx.x < 128){ float v = cols[threadIdx.x]; if (v != 0.f) atomicAdd(&rs0[threadIdx.x], v); }
}

__global__ void cg_ap(const int* __restrict__ flags, int k, const float* __restrict__ P,
                      const unsigned* __restrict__ Pbf,
                      const int* __restrict__ offb, const int* __restrict__ adjn, const float* __restrict__ adjw,
                      const float* __restrict__ deg, float* __restrict__ AP, float* __restrict__ dn){
  if (flags[k]) return;
  __shared__ float cols[128];
  if (threadIdx.x < 128) cols[threadIdx.x] = 0.f;
  __syncthreads();
  int wid = threadIdx.x >> 6, lane = threadIdx.x & 63;
  int node = blockIdx.x*4 + wid;
  if (node < N){
    float2 acc = {0.f,0.f};
    int p0 = offb[node], p1 = offb[node+1];
    int p = p0;
    for (; p+8 <= p1; p += 8){
      int jj[8]; float ww[8];
      #pragma unroll
      for (int t=0;t<8;t++){ jj[t] = adjn[p+t]; ww[t] = adjw[p+t]; }
      unsigned uu[8];
      #pragma unroll
      for (int t=0;t<8;t++) uu[t] = Pbf[(long)jj[t]*64 + lane];
      #pragma unroll
      for (int t=0;t<8;t++){ float2 v = ub2f2(uu[t]); acc.x += ww[t]*v.x; acc.y += ww[t]*v.y; }
    }
    for (; p<p1; p++){
      int j = adjn[p]; float w = adjw[p];
      float2 v = ub2f2(Pbf[(long)j*64 + lane]);
      acc.x += w*v.x; acc.y += w*v.y;
    }
    float dg = deg[node];
    float2 pi = ((const float2*)P)[(long)node*64 + lane];
    float2 ap;
    ap.x = pi.x + DT*(dg*pi.x - acc.x);
    ap.y = pi.y + DT*(dg*pi.y - acc.y);
    ((float2*)AP)[(long)node*64 + lane] = ap;
    atomicAdd(&cols[lane*2],   pi.x*ap.x);
    atomicAdd(&cols[lane*2+1], pi.y*ap.y);
  }
  __syncthreads();
  if (threadIdx.x < 128){ float v = cols[threadIdx.x]; if (v != 0.f) atomicAdd(&dn[threadIdx.x], v); }
}

__global__ void cg_xr(const int* __restrict__ flags, int k, const float* __restrict__ rs, const float* __restrict__ dn,
                      const float* __restrict__ P, const float* __restrict__ AP,
                      float* __restrict__ X, float* __restrict__ R, float* __restrict__ rsn){
  if (flags[k]) return;
  __shared__ float cols[128];
  if (threadIdx.x < 128) cols[threadIdx.x] = 0.f;
  __syncthreads();
  int total = N*32;
  for (int idx = blockIdx.x*blockDim.x + threadIdx.x; idx < total; idx += gridDim.x*blockDim.x){
    int c4 = (idx & 31)*4;
    float a0 = rs[c4+0]/(dn[c4+0]+1e-16f);
    float a1 = rs[c4+1]/(dn[c4+1]+1e-16f);
    float a2 = rs[c4+2]/(dn[c4+2]+1e-16f);
    float a3 = rs[c4+3]/(dn[c4+3]+1e-16f);
    float4 p  = ((const float4*)P)[idx];
    float4 ap = ((const float4*)AP)[idx];
    float4 x  = ((float4*)X)[idx];
    float4 r  = ((float4*)R)[idx];
    x.x += a0*p.x; x.y += a1*p.y; x.z += a2*p.z; x.w += a3*p.w;
    r.x -= a0*ap.x; r.y -= a1*ap.y; r.z -= a2*ap.z; r.w -= a3*ap.w;
    ((float4*)X)[idx] = x; ((float4*)R)[idx] = r;
    atomicAdd(&cols[c4+0], r.x*r.x);
    atomicAdd(&cols[c4+1], r.y*r.y);
    atomicAdd(&cols[c4+2], r.z*r.z);
    atomicAdd(&cols[c4+3], r.w*r.w);
  }
  __syncthreads();
  if (threadIdx.x < 128){ float v = cols[threadIdx.x]; if (v != 0.f) atomicAdd(&rsn[threadIdx.x], v); }
}

__global__ void cg_p(const int* __restrict__ flags, int k, const float* __restrict__ rsn, const float* __restrict__ rsp,
                     const float* __restrict__ R, float* __restrict__ P, short* __restrict__ Pbf,
                     int* __restrict__ flags_w){
  if (flags[k]){ if (threadIdx.x==0) flags_w[k+1] = 1; return; }
  __shared__ float red[4];
  __shared__ int done_s;
  float v = (threadIdx.x < 128) ? rsn[threadIdx.x] : -1.f;
  #pragma unroll
  for (int d=32; d; d>>=1) v = fmaxf(v, __shfl_xor(v, d));
  if ((threadIdx.x & 63)==0) red[threadIdx.x>>6] = v;
  __syncthreads();
  if (threadIdx.x==0){
    float m = fmaxf(fmaxf(red[0],red[1]), fmaxf(red[2],red[3]));
    done_s = (m < TOL2) ? 1 : 0;
  }
  __syncthreads();
  if (done_s){ if (threadIdx.x==0) flags_w[k+1] = 1; return; }
  int total = N*32;
  for (int idx = blockIdx.x*blockDim.x + threadIdx.x; idx < total; idx += gridDim.x*blockDim.x){
    int c4 = (idx & 31)*4;
    float b0 = rsn[c4+0]/(rsp[c4+0]+1e-16f);
    float b1v = rsn[c4+1]/(rsp[c4+1]+1e-16f);
    float b2v = rsn[c4+2]/(rsp[c4+2]+1e-16f);
    float b3 = rsn[c4+3]/(rsp[c4+3]+1e-16f);
    float4 r = ((const float4*)R)[idx];
    float4 p = ((float4*)P)[idx];
    p.x = r.x + b0*p.x; p.y = r.y + b1v*p.y; p.z = r.z + b2v*p.z; p.w = r.w + b3*p.w;
    ((float4*)P)[idx] = p;
    short4 pb; pb.x=f2b(p.x); pb.y=f2b(p.y); pb.z=f2b(p.z); pb.w=f2b(p.w);
    ((short4*)Pbf)[idx] = pb;
  }
}

// ---------------- AFM ----------------
__global__ void isd_kernel(const float* __restrict__ deg, float* __restrict__ isd){
  int i = blockIdx.x*256 + threadIdx.x;
  if (i < N) isd[i] = sqrtf(1.f / fmaxf(deg[i], 1e-8f));
}

// out = alpha*tildeL(Min) - beta*Mprev; gathers bf16 Minb; optional bf16 out
__global__ void tl_apply(const float* __restrict__ Min, const unsigned* __restrict__ Minb,
                         const float* __restrict__ Mprev, float alpha, float beta,
                         const float* __restrict__ isd, const float* __restrict__ deg, const int* __restrict__ offb,
                         const int* __restrict__ adjn, const float* __restrict__ adjw2,
                         float* __restrict__ out, unsigned* __restrict__ outb){
  int wid = threadIdx.x >> 6, lane = threadIdx.x & 63;
  int node = blockIdx.x*4 + wid;
  if (node >= N) return;
  float2 acc = {0.f,0.f};
  int p0 = offb[node], p1 = offb[node+1];
  int p = p0;
  for (; p+8 <= p1; p += 8){
    int jj[8]; float ww[8];
    #pragma unroll
    for (int t=0;t<8;t++){ jj[t] = adjn[p+t]; ww[t] = adjw2[p+t]; }
    unsigned uu[8];
    #pragma unroll
    for (int t=0;t<8;t++) uu[t] = Minb[(long)jj[t]*64 + lane];
    #pragma unroll
    for (int t=0;t<8;t++){ float2 v = ub2f2(uu[t]); acc.x += ww[t]*v.x; acc.y += ww[t]*v.y; }
  }
  for (; p<p1; p++){
    int j = adjn[p]; float w = adjw2[p];
    float2 v = ub2f2(Minb[(long)j*64 + lane]);
    acc.x += w*v.x; acc.y += w*v.y;
  }
  float ii = isd[node]; float dg = deg[node];
  float2 mi = ((const float2*)Min)[(long)node*64 + lane];
  float2 pv = ((const float2*)Mprev)[(long)node*64 + lane];
  float2 o;
  o.x = alpha*(mi.x + ii*(dg*ii*mi.x - acc.x)) - beta*pv.x;
  o.y = alpha*(mi.y + ii*(dg*ii*mi.y - acc.y)) - beta*pv.y;
  ((float2*)out)[(long)node*64 + lane] = o;
  if (outb) outb[(long)node*64 + lane] = pack2(o.x, o.y);
}

__global__ void combine_fused(const float* __restrict__ h, const float* __restrict__ X,
                              const float* __restrict__ T1, const float* __restrict__ T2, const float* __restrict__ T3,
                              const float* __restrict__ gamma, const float* __restrict__ asvr, const float* __restrict__ aafm,
                              short* __restrict__ fusedb){
  float g0=gamma[0], g1=gamma[1], g2=gamma[2], g3=gamma[3];
  float mg = fmaxf(fmaxf(g0,g1), fmaxf(g2,g3));
  float e0=expf(g0-mg), e1=expf(g1-mg), e2=expf(g2-mg), e3=expf(g3-mg);
  float s = e0+e1+e2+e3;
  float a0=e0/s, a1=e1/s, a2=e2/s, a3=e3/s;
  float s1 = 1.f/(1.f+expf(-asvr[0]));
  float s2 = 1.f/(1.f+expf(-aafm[0]));
  int total = N*H;
  for (int i = blockIdx.x*blockDim.x + threadIdx.x; i < total; i += gridDim.x*blockDim.x){
    float hv = h[i];
    float v = hv + s1*X[i] + s2*(a0*hv + a1*T1[i] + a2*T2[i] + a3*T3[i]);
    fusedb[i] = f2b(v);
  }
}

// ---------------- GAT ----------------
__global__ void esed1_kernel(const float* __restrict__ xw1, const float* __restrict__ a1s, const float* __restrict__ a1d,
                             float* __restrict__ es, float* __restrict__ ed){
  int id = blockIdx.x*256 + threadIdx.x;
  if (id < N*8){
    int n = id >> 3, hd = id & 7;
    const float* xr = xw1 + (long)n*64 + hd*8;
    float s=0.f, d=0.f;
    #pragma unroll
    for (int c=0;c<8;c++){ float v = xr[c]; s += v*a1s[hd*8+c]; d += v*a1d[hd*8+c]; }
    es[id]=s; ed[id]=d;
  }
}

// single-pass online-softmax GAT layer 1; gathers bf16 xw1 rows
__global__ void gat1(const int* __restrict__ offi, const int* __restrict__ adjsrc,
                     const float* __restrict__ es, const float* __restrict__ ed,
                     const float* __restrict__ xw1, const unsigned short* __restrict__ xw1b,
                     const float* __restrict__ b1, float* __restrict__ o1){
  int wid = threadIdx.x >> 6, lane = threadIdx.x & 63;
  int d = blockIdx.x*4 + wid;
  if (d >= N) return;
  int hd = lane >> 3;
  float edd = ed[d*8+hd];
  float esd = es[d*8+hd];
  auto lk = [](float x){ return x >= 0.f ? x : 0.2f*x; };
  float m = lk(esd+edd);
  float den = 1.f;
  float num = xw1[(long)d*64 + lane];
  int p0 = offi[d], p1 = offi[d+1];
  int p = p0;
  for (; p+4 <= p1; p += 4){
    int ss[4];
    #pragma unroll
    for (int t=0;t<4;t++) ss[t] = adjsrc[p+t];
    float ee[4]; unsigned short uv[4];
    #pragma unroll
    for (int t=0;t<4;t++){ ee[t] = es[ss[t]*8+hd]; uv[t] = xw1b[(long)ss[t]*64 + lane]; }
    #pragma unroll
    for (int t=0;t<4;t++){
      float e = lk(ee[t]+edd);
      float mn = fmaxf(m, e);
      float sc = expf(m-mn), ex = expf(e-mn);
      den = den*sc + ex;
      num = num*sc + ex*ub2f(uv[t]);
      m = mn;
    }
  }
  for (; p<p1; p++){
    int s = adjsrc[p];
    float e = lk(es[s*8+hd]+edd);
    float v = ub2f(xw1b[(long)s*64 + lane]);
    float mn = fmaxf(m, e);
    float sc = expf(m-mn), ex = expf(e-mn);
    den = den*sc + ex;
    num = num*sc + ex*v;
    m = mn;
  }
  float o = num/(den+1e-16f) + b1[lane];
  o1[(long)d*64+lane] = o > 0.f ? o : expm1f(o);
}

__global__ void xw2_kernel(const float* __restrict__ o1, const float* __restrict__ W2, float* __restrict__ xw2){
  __shared__ float w2s[64*16];
  for (int i=threadIdx.x; i<64*16; i+=256) w2s[i] = W2[i];
  __syncthreads();
  int id = blockIdx.x*256 + threadIdx.x;
  if (id < N*16){
    int n = id >> 4, c = id & 15;
    const float* orow = o1 + (long)n*64;
    float acc = 0.f;
    #pragma unroll
    for (int kk=0; kk<64; kk++) acc += orow[kk]*w2s[kk*16+c];
    xw2[id] = acc;
  }
}

__global__ void esed2_kernel(const float* __restrict__ xw2, const float* __restrict__ a2s, const float* __restrict__ a2d,
                             float* __restrict__ es2, float* __restrict__ ed2){
  int n = blockIdx.x*256 + threadIdx.x;
  if (n < N){
    float s=0.f, d=0.f;
    #pragma unroll
    for (int c=0;c<16;c++){ float v = xw2[(long)n*16+c]; s += v*a2s[c]; d += v*a2d[c]; }
    es2[n]=s; ed2[n]=d;
  }
}

// single-pass online-softmax GAT layer 2 (1 head, 16 ch)
__global__ void gat2(const int* __restrict__ offi, const int* __restrict__ adjsrc,
                     const float* __restrict__ es2, const float* __restrict__ ed2,
                     const float* __restrict__ xw2, const float* __restrict__ b2w, float* __restrict__ out){
  int wid = threadIdx.x >> 6, lane = threadIdx.x & 63;
  int d = blockIdx.x*4 + wid;
  if (d >= N) return;
  auto lk = [](float x){ return x >= 0.f ? x : 0.2f*x; };
  float edd = ed2[d];
  float m = lk(es2[d]+edd);
  float den = 1.f;
  float num = (lane<16) ? xw2[(long)d*16+lane] : 0.f;
  int p0 = offi[d], p1 = offi[d+1];
  int p = p0;
  for (; p+4 <= p1; p += 4){
    int ss[4];
    #pragma unroll
    for (int t=0;t<4;t++) ss[t] = adjsrc[p+t];
    float ee[4], vv[4];
    #pragma unroll
    for (int t=0;t<4;t++){ ee[t] = es2[ss[t]]; vv[t] = (lane<16) ? xw2[(long)ss[t]*16+lane] : 0.f; }
    #pragma unroll
    for (int t=0;t<4;t++){
      float e = lk(ee[t]+edd);
      float mn = fmaxf(m, e);
      float sc = expf(m-mn), ex = expf(e-mn);
      den = den*sc + ex;
      num = num*sc + ex*vv[t];
      m = mn;
    }
  }
  for (; p<p1; p++){
    int s = adjsrc[p];
    float e = lk(es2[s]+edd);
    float v = (lane<16) ? xw2[(long)s*16+lane] : 0.f;
    float mn = fmaxf(m, e);
    float sc = expf(m-mn), ex = expf(e-mn);
    den = den*sc + ex;
    num = num*sc + ex*v;
    m = mn;
  }
  if (lane<16) out[(long)d*16+lane] = num/(den+1e-16f) + b2w[lane];
}

// ---------------- host ----------------
extern "C" void kernel_launch(void* const* d_in, const int* in_sizes, int n_in,
                              void* d_out, int out_size, void* d_ws, size_t ws_size,
                              hipStream_t stream){
  const float* x     = (const float*)d_in[0];
  const int*   ei    = (const int*)  d_in[1];
  const float* W_in  = (const float*)d_in[2];
  const float* b_in  = (const float*)d_in[3];
  const float* ln_g  = (const float*)d_in[4];
  const float* ln_b  = (const float*)d_in[5];
  const float* W_sh  = (const float*)d_in[6];
  const float* gamma = (const float*)d_in[7];
  const float* asvr  = (const float*)d_in[8];
  const float* aafm  = (const float*)d_in[9];
  const float* W1    = (const float*)d_in[10];
  const float* a1s   = (const float*)d_in[11];
  const float* a1d   = (const float*)d_in[12];
  const float* b1    = (const float*)d_in[13];
  const float* W2    = (const float*)d_in[14];
  const float* a2s   = (const float*)d_in[15];
  const float* a2d   = (const float*)d_in[16];
  const float* b2w   = (const float*)d_in[17];

  char* ws = (char*)d_ws;
  size_t off = 0;
  auto alloc = [&](size_t bytes)->char*{ char* p = ws + off; off = (off + bytes + 255) & ~(size_t)255; return p; };
  float* h    = (float*)alloc((size_t)N*H*4);
  float* big1 = (float*)alloc((size_t)N*H*4); // preLN -> hw(f32, unused) -> AP -> T3
  float* X    = (float*)alloc((size_t)N*H*4);
  float* Rb   = (float*)alloc((size_t)N*H*4); // R -> T1
  float* Pb   = (float*)alloc((size_t)N*H*4); // P -> T2
  short* hbf  = (short*)alloc((size_t)N*H*2); // bf16(h): gemm input + tl1 gather
  short* fusedb = (short*)alloc((size_t)N*H*2);
  short* bufA = (short*)alloc((size_t)N*H*2); // hwb -> Pbf -> T1b
  short* bufB = (short*)alloc((size_t)N*H*2); // T2b -> xw1b
  float* wLp  = (float*)alloc((size_t)E*4);
  float* deg  = (float*)alloc((size_t)N*4);
  float* isd  = (float*)alloc((size_t)N*4);
  int* cntb   = (int*)alloc((size_t)N*4);
  int* cnti   = (int*)alloc((size_t)N*4);
  int* offb   = (int*)alloc((size_t)(N+1)*4);
  int* offi   = (int*)alloc((size_t)(N+1)*4);
  int* adjn   = (int*)alloc((size_t)2*E*4);
  int* adjeid = (int*)alloc((size_t)2*E*4);
  float* adjw = (float*)alloc((size_t)2*E*4);
  int* adjsrc = (int*)alloc((size_t)E*4);
  short* BtIn = (short*)alloc((size_t)IN*H*2);
  short* Wst  = (short*)alloc((size_t)H*H*2);
  short* W1t  = (short*)alloc((size_t)H*64*2);
  float* rs_all = (float*)alloc((size_t)(MAXITER+1)*128*4);
  float* dn_all = (float*)alloc((size_t)MAXITER*128*4);
  int* flags  = (int*)alloc((size_t)(MAXITER+1)*4);

  // aliases (regions dead by the time these are written)
  short* xbf = (short*)X;               // N*IN bf16 = 51.2MB, spans X+Rb (dead until cg_init)
  float* adjw2 = (float*)adjeid;        // adjeid dead after adj_weights
  short* hwb  = bufA;                   // bf16 hw: gemm<H,H> -> edge_weights
  short* Pbf  = bufA;                   // CG bf16 P: cg_init -> CG end
  short* T1b  = bufA;                   // tl1 -> tl2
  short* T2b  = bufB;                   // tl2 -> tl3
  short* xw1b = bufB;                   // gemm<H,64> -> gat1
  float* xw1 = h;                       // after combine, h region reused
  float* o1  = h + (size_t)N*64;
  float* es  = X;                       // after combine, X region reused
  float* ed  = X + (size_t)N*8;
  float* xw2 = X + (size_t)N*16;
  float* es2 = X + (size_t)N*32;
  float* ed2 = X + (size_t)N*33;
  float* AP  = big1;
  float* T1 = Rb; float* T2 = Pb; float* T3 = big1;

  hipMemsetAsync(deg, 0, (size_t)N*4, stream);
  hipMemsetAsync(cntb, 0, (size_t)N*4, stream);
  hipMemsetAsync(cnti, 0, (size_t)N*4, stream);
  hipMemsetAsync(rs_all, 0, (size_t)(MAXITER+1)*128*4, stream);
  hipMemsetAsync(dn_all, 0, (size_t)MAXITER*128*4, stream);
  hipMemsetAsync(flags, 0, (size_t)(MAXITER+1)*4, stream);

  conv_x<<<(int)(((long)N*IN/4 + 255)/256),256,0,stream>>>(x, xbf, (long)N*IN/4);
  conv_transpose<<<(IN*H+255)/256,256,0,stream>>>(W_in, BtIn, IN, H);
  conv_transpose<<<(H*H+255)/256,256,0,stream>>>(W_sh, Wst, H, H);
  conv_transpose<<<(H*64+255)/256,256,0,stream>>>(W1, W1t, H, 64);

  int gm = (N+63)/64;
  mfma_gemm<IN,H,false><<<gm,256,0,stream>>>(xbf, BtIn, big1, nullptr, N);
  ln_sigmoid<<<N,128,0,stream>>>(big1, b_in, ln_g, ln_b, h, hbf);
  mfma_gemm<H,H,true><<<gm,256,0,stream>>>(hbf, Wst, big1, hwb, N);

  count_deg<<<(E+255)/256,256,0,stream>>>(ei, cntb, cnti);
  scan_excl<<<1,1024,0,stream>>>(cntb, N, offb);
  scan_excl<<<1,1024,0,stream>>>(cnti, N, offi);
  hipMemsetAsync(cntb, 0, (size_t)N*4, stream);
  hipMemsetAsync(cnti, 0, (size_t)N*4, stream);
  fill_adj<<<(E+255)/256,256,0,stream>>>(ei, offb, offi, cntb, cnti, adjn, adjeid, adjsrc);

  edge_weights<<<(E+3)/4,256,0,stream>>>(ei, (const unsigned*)hwb, wLp, deg);
  adj_weights<<<(2*E+255)/256,256,0,stream>>>(adjeid, wLp, adjw);

  cg_init<<<1024,256,0,stream>>>(h, X, Rb, Pb, Pbf, rs_all);
  for (int k=0; k<MAXITER; k++){
    cg_ap<<<(N+3)/4,256,0,stream>>>(flags, k, Pb, (const unsigned*)Pbf, offb, adjn, adjw, deg, AP, dn_all+(size_t)k*128);
    cg_xr<<<1024,256,0,stream>>>(flags, k, rs_all+(size_t)k*128, dn_all+(size_t)k*128, Pb, AP, X, Rb, rs_all+(size_t)(k+1)*128);
    cg_p<<<1024,256,0,stream>>>(flags, k, rs_all+(size_t)(k+1)*128, rs_all+(size_t)k*128, Rb, Pb, Pbf, flags);
  }

  isd_kernel<<<(N+255)/256,256,0,stream>>>(deg, isd);
  adj_w_isd<<<(2*E+255)/256,256,0,stream>>>(adjn, adjw, isd, adjw2);
  tl_apply<<<(N+3)/4,256,0,stream>>>(h,  (const unsigned*)hbf, h,  1.f, 0.f, isd, deg, offb, adjn, adjw2, T1, (unsigned*)T1b);
  tl_apply<<<(N+3)/4,256,0,stream>>>(T1, (const unsigned*)T1b, h,  2.f, 1.f, isd, deg, offb, adjn, adjw2, T2, (unsigned*)T2b);
  tl_apply<<<(N+3)/4,256,0,stream>>>(T2, (const unsigned*)T2b, T1, 2.f, 1.f, isd, deg, offb, adjn, adjw2, T3, nullptr);
  combine_fused<<<1024,256,0,stream>>>(h, X, T1, T2, T3, gamma, asvr, aafm, fusedb);

  mfma_gemm<H,64,true><<<gm,256,0,stream>>>(fusedb, W1t, xw1, xw1b, N);
  esed1_kernel<<<(N*8+255)/256,256,0,stream>>>(xw1, a1s, a1d, es, ed);
  gat1<<<(N+3)/4,256,0,stream>>>(offi, adjsrc, es, ed, xw1, (const unsigned short*)xw1b, b1, o1);
  xw2_kernel<<<(N*16+255)/256,256,0,stream>>>(o1, W2, xw2);
  esed2_kernel<<<(N+255)/256,256,0,stream>>>(xw2, a2s, a2d, es2, ed2);
  gat2<<<(N+3)/4,256,0,stream>>>(offi, adjsrc, es2, ed2, xw2, b2w, (float*)d_out);
}

// Round 5
// 1327.467 us; speedup vs baseline: 1.6021x; 1.3910x over previous
//
#include <hip/hip_runtime.h>

// SVRSheafNet forward on MI355X. FP32 inputs, int32 edge_index, FP32 out.
// Key lessons baked in: (1) node-row gathers stored bf16 (half the lines);
// (2) dot-product reductions must avoid hot-line atomics: register-accumulate,
// few blocks, and one cache line per reduction column (RPAD=32 floats).

constexpr int N = 50000;
constexpr int E = 512000;
constexpr int IN = 512;
constexpr int H = 128;
constexpr float DT = 0.1f;
constexpr float EPSC = 1e-3f;
constexpr float TOL2 = 1e-8f;
constexpr int MAXITER = 20;
constexpr int RPAD = 32;   // floats between reduction columns (one 128B line each)

typedef __attribute__((ext_vector_type(8))) short bf16x8;
typedef __attribute__((ext_vector_type(4))) float f32x4;

__device__ inline short f2b(float f){ unsigned u; __builtin_memcpy(&u,&f,4); unsigned r = u + 0x7FFFu + ((u>>16)&1u); return (short)(r>>16); }
__device__ inline float2 ub2f2(unsigned u){
  unsigned lo = u << 16, hi = u & 0xFFFF0000u;
  float a,b; __builtin_memcpy(&a,&lo,4); __builtin_memcpy(&b,&hi,4);
  return (float2){a,b};
}
__device__ inline float ub2f(unsigned short s){
  unsigned u = ((unsigned)s) << 16; float f; __builtin_memcpy(&f,&u,4); return f;
}
__device__ inline unsigned pack2(float x, float y){
  return (unsigned)(unsigned short)f2b(x) | ((unsigned)(unsigned short)f2b(y) << 16);
}

// ---------------- fp32 -> bf16 conversions ----------------
__global__ void conv_x(const float* __restrict__ A, short* __restrict__ out, long total4){
  long idx = (long)blockIdx.x*256 + threadIdx.x;
  if (idx < total4){
    float4 v = ((const float4*)A)[idx];
    short4 o; o.x=f2b(v.x); o.y=f2b(v.y); o.z=f2b(v.z); o.w=f2b(v.w);
    ((short4*)out)[idx] = o;
  }
}

// B[K][Nc] fp32 -> Bt[Nc][K] bf16
__global__ void conv_transpose(const float* __restrict__ B, short* __restrict__ Bt, int K, int Nc){
  int id = blockIdx.x*256 + threadIdx.x;
  if (id < K*Nc){ int k = id / Nc, n = id - k*Nc; Bt[(long)n*K + k] = f2b(B[id]); }
}

// ---------------- MFMA GEMM: A[M,K]bf16 @ Bt[TN,K]bf16 -> C[M,TN]f32 (+ optional bf16 copy) ----------------
template<int K, int TN, bool WB16>
__global__ __launch_bounds__(256) void mfma_gemm(const short* __restrict__ A, const short* __restrict__ Bt,
                                                 float* __restrict__ C, short* __restrict__ Cb, int M){
  constexpr int NT = TN/16;
  __shared__ short lA[64][40];
  __shared__ short lB[TN][40];
  int wid = threadIdx.x >> 6, lane = threadIdx.x & 63;
  int ln15 = lane & 15, quad = lane >> 4;
  int m0 = blockIdx.x * 64;
  f32x4 acc[NT];
  #pragma unroll
  for (int t=0;t<NT;t++) acc[t] = (f32x4){0.f,0.f,0.f,0.f};
  for (int k0=0; k0<K; k0+=32){
    {
      int row = threadIdx.x >> 2, q = threadIdx.x & 3;
      int gr = m0 + row;
      uint4 v = {0u,0u,0u,0u};
      if (gr < M) v = *(const uint4*)(A + (long)gr*K + k0 + q*8);
      *(uint4*)&lA[row][q*8] = v;
    }
    if constexpr (TN==128){
      int row = threadIdx.x >> 1, hh = threadIdx.x & 1;
      const uint4* src = (const uint4*)(Bt + (long)row*K + k0 + hh*16);
      *(uint4*)&lB[row][hh*16]   = src[0];
      *(uint4*)&lB[row][hh*16+8] = src[1];
    } else {
      int row = threadIdx.x >> 2, q = threadIdx.x & 3;
      *(uint4*)&lB[row][q*8] = *(const uint4*)(Bt + (long)row*K + k0 + q*8);
    }
    __syncthreads();
    bf16x8 a = *(bf16x8*)&lA[wid*16+ln15][quad*8];
    #pragma unroll
    for (int t=0;t<NT;t++){
      bf16x8 b = *(bf16x8*)&lB[t*16+ln15][quad*8];
      acc[t] = __builtin_amdgcn_mfma_f32_16x16x32_bf16(a, b, acc[t], 0, 0, 0);
    }
    __syncthreads();
  }
  int mr = m0 + wid*16 + quad*4;
  #pragma unroll
  for (int t=0;t<NT;t++){
    #pragma unroll
    for (int r=0;r<4;r++){
      int gr = mr + r;
      if (gr < M){
        C[(long)gr*TN + t*16 + ln15] = acc[t][r];
        if constexpr (WB16) Cb[(long)gr*TN + t*16 + ln15] = f2b(acc[t][r]);
      }
    }
  }
}

// ---------------- LayerNorm + sigmoid ----------------
__global__ void ln_sigmoid(const float* __restrict__ pre, const float* __restrict__ b_in,
                           const float* __restrict__ g, const float* __restrict__ bb,
                           float* __restrict__ h, short* __restrict__ hbf){
  int row = blockIdx.x; int t = threadIdx.x; // 128 threads
  float v = pre[(long)row*H + t] + b_in[t];
  __shared__ float sm[2];
  int lane = t & 63, wid = t >> 6;
  float x = v;
  #pragma unroll
  for (int d=32; d; d>>=1) x += __shfl_xor(x, d);
  if (lane==0) sm[wid] = x;
  __syncthreads();
  float mean = (sm[0]+sm[1]) * (1.f/128.f);
  float dv = v - mean;
  __syncthreads();
  x = dv*dv;
  #pragma unroll
  for (int d=32; d; d>>=1) x += __shfl_xor(x, d);
  if (lane==0) sm[wid] = x;
  __syncthreads();
  float var = (sm[0]+sm[1]) * (1.f/128.f);
  float y = dv * rsqrtf(var + 1e-5f) * g[t] + bb[t];
  float hv = 1.f/(1.f+expf(-y));
  h[(long)row*H+t] = hv;
  hbf[(long)row*H+t] = f2b(hv);
}

// ---------------- CSR build ----------------
__global__ void count_deg(const int* __restrict__ ei, int* cntb, int* cnti){
  int e = blockIdx.x*256 + threadIdx.x;
  if (e < E){
    int r = ei[e], c = ei[E+e];
    atomicAdd(&cntb[r],1); atomicAdd(&cntb[c],1); atomicAdd(&cnti[c],1);
  }
}

__global__ __launch_bounds__(1024) void scan_excl(const int* __restrict__ cnt, int n, int* __restrict__ off){
  __shared__ int ws_[16];
  __shared__ int carry;
  if (threadIdx.x==0) carry = 0;
  __syncthreads();
  int lane = threadIdx.x & 63, wid = threadIdx.x >> 6;
  for (int base=0; base<n; base += 1024){
    int i = base + threadIdx.x;
    int v = (i<n) ? cnt[i] : 0;
    int x = v;
    #pragma unroll
    for (int d=1; d<64; d<<=1){ int y = __shfl_up(x, d); if (lane>=d) x += y; }
    if (lane==63) ws_[wid] = x;
    __syncthreads();
    if (threadIdx.x==0){ int acc=0; for (int w=0;w<16;w++){ int t=ws_[w]; ws_[w]=acc; acc+=t; } }
    __syncthreads();
    int excl = carry + ws_[wid] + x - v;
    if (i<n) off[i] = excl;
    __syncthreads();
    if (threadIdx.x==1023) carry = carry + ws_[15] + x;
    __syncthreads();
  }
  if (threadIdx.x==0) off[n] = carry;
}

__global__ void fill_adj(const int* __restrict__ ei, const int* __restrict__ offb, const int* __restrict__ offi,
                         int* curb, int* curi, int* adjn, int* adjeid, int* adjsrc){
  int e = blockIdx.x*256 + threadIdx.x;
  if (e < E){
    int r = ei[e], c = ei[E+e];
    int p = offb[r] + atomicAdd(&curb[r],1); adjn[p]=c; adjeid[p]=e;
    p     = offb[c] + atomicAdd(&curb[c],1); adjn[p]=r; adjeid[p]=e;
    p     = offi[c] + atomicAdd(&curi[c],1); adjsrc[p]=r;
  }
}

__global__ void adj_weights(const int* __restrict__ adjeid, const float* __restrict__ wL, float* __restrict__ adjw){
  int p = blockIdx.x*256 + threadIdx.x;
  if (p < 2*E) adjw[p] = wL[adjeid[p]];
}

// adjw2[p] = adjw[p] * isd[adjn[p]]
__global__ void adj_w_isd(const int* __restrict__ adjn, const float* __restrict__ adjw,
                          const float* __restrict__ isd, float* __restrict__ adjw2){
  int p = blockIdx.x*256 + threadIdx.x;
  if (p < 2*E) adjw2[p] = adjw[p] * isd[adjn[p]];
}

// ---------------- per-edge sheaf weights (bf16 hw rows) ----------------
__global__ void edge_weights(const int* __restrict__ ei, const unsigned* __restrict__ hwb,
                             float* __restrict__ wL, float* __restrict__ deg){
  int wid = threadIdx.x >> 6, lane = threadIdx.x & 63;
  int e = blockIdx.x*4 + wid;
  if (e >= E) return;
  int r = ei[e], c = ei[E+e];
  float2 fr = ub2f2(hwb[(long)r*64 + lane]);
  float2 fc = ub2f2(hwb[(long)c*64 + lane]);
  float dx = fr.x-fc.x, dy = fr.y-fc.y;
  float sd = dx*dx + dy*dy;
  float sr = fr.x*fr.x + fr.y*fr.y;
  #pragma unroll
  for (int d=32; d; d>>=1){ sd += __shfl_xor(sd,d); sr += __shfl_xor(sr,d); }
  if (lane==0){
    float C  = sd * (1.0f/128.0f);
    float P0 = fminf(fmaxf(expf(-C*(1.0f/EPSC)), 1e-3f), 1.0f);
    float Ps = fminf(fmaxf(expf(logf(P0+1e-12f) - C*(1.0f/EPSC)), 1e-3f), 1.0f);
    float w  = 0.7f*P0 + 0.3f*Ps;
    float wl = w*w*sr*(1.0f/128.0f);
    wL[e] = wl;
    atomicAdd(&deg[r], wl);
    atomicAdd(&deg[c], wl);
  }
}

// ---------------- CG (reductions: padded columns, one line each) ----------------
__global__ void cg_init(const float* __restrict__ h, float* __restrict__ X, float* __restrict__ R,
                        float* __restrict__ P, short* __restrict__ Pbf, float* __restrict__ rs0){
  __shared__ float cols[128];
  if (threadIdx.x < 128) cols[threadIdx.x] = 0.f;
  __syncthreads();
  int total = N*32;
  float4 z = {0,0,0,0};
  for (int idx = blockIdx.x*blockDim.x + threadIdx.x; idx < total; idx += gridDim.x*blockDim.x){
    float4 hv = ((const float4*)h)[idx];
    ((float4*)X)[idx] = z; ((float4*)R)[idx] = hv; ((float4*)P)[idx] = hv;
    short4 pb; pb.x=f2b(hv.x); pb.y=f2b(hv.y); pb.z=f2b(hv.z); pb.w=f2b(hv.w);
    ((short4*)Pbf)[idx] = pb;
    int c4 = (idx & 31)*4;
    atomicAdd(&cols[c4+0], hv.x*hv.x);
    atomicAdd(&cols[c4+1], hv.y*hv.y);
    atomicAdd(&cols[c4+2], hv.z*hv.z);
    atomicAdd(&cols[c4+3], hv.w*hv.w);
  }
  __syncthreads();
  if (threadIdx.x < 128){ float v = cols[threadIdx.x]; if (v != 0.f) atomicAdd(&rs0[threadIdx.x*RPAD], v); }
}

// grid-stride over nodes; per-wave register accumulation of its two dn columns
__global__ __launch_bounds__(256) void cg_ap(const int* __restrict__ flags, int k, const float* __restrict__ P,
                      const unsigned* __restrict__ Pbf,
                      const int* __restrict__ offb, const int* __restrict__ adjn, const float* __restrict__ adjw,
                      const float* __restrict__ deg, float* __restrict__ AP, float* __restrict__ dn){
  if (flags[k]) return;
  __shared__ float cols[128];
  if (threadIdx.x < 128) cols[threadIdx.x] = 0.f;
  __syncthreads();
  int wid = threadIdx.x >> 6, lane = threadIdx.x & 63;
  int gw = blockIdx.x*4 + wid;
  int nw = gridDim.x*4;
  float dnx = 0.f, dny = 0.f;
  for (int node = gw; node < N; node += nw){
    float2 acc = {0.f,0.f};
    int p0 = offb[node], p1 = offb[node+1];
    int p = p0;
    for (; p+8 <= p1; p += 8){
      int jj[8]; float ww[8];
      #pragma unroll
      for (int t=0;t<8;t++){ jj[t] = adjn[p+t]; ww[t] = adjw[p+t]; }
      unsigned uu[8];
      #pragma unroll
      for (int t=0;t<8;t++) uu[t] = Pbf[(long)jj[t]*64 + lane];
      #pragma unroll
      for (int t=0;t<8;t++){ float2 v = ub2f2(uu[t]); acc.x += ww[t]*v.x; acc.y += ww[t]*v.y; }
    }
    for (; p<p1; p++){
      int j = adjn[p]; float w = adjw[p];
      float2 v = ub2f2(Pbf[(long)j*64 + lane]);
      acc.x += w*v.x; acc.y += w*v.y;
    }
    float dg = deg[node];
    float2 pi = ((const float2*)P)[(long)node*64 + lane];
    float2 ap;
    ap.x = pi.x + DT*(dg*pi.x - acc.x);
    ap.y = pi.y + DT*(dg*pi.y - acc.y);
    ((float2*)AP)[(long)node*64 + lane] = ap;
    dnx += pi.x*ap.x; dny += pi.y*ap.y;
  }
  atomicAdd(&cols[lane*2],   dnx);
  atomicAdd(&cols[lane*2+1], dny);
  __syncthreads();
  if (threadIdx.x < 128){ float v = cols[threadIdx.x]; if (v != 0.f) atomicAdd(&dn[threadIdx.x*RPAD], v); }
}

__global__ void cg_xr(const int* __restrict__ flags, int k, const float* __restrict__ rs, const float* __restrict__ dn,
                      const float* __restrict__ P, const float* __restrict__ AP,
                      float* __restrict__ X, float* __restrict__ R, float* __restrict__ rsn){
  if (flags[k]) return;
  __shared__ float cols[128];
  if (threadIdx.x < 128) cols[threadIdx.x] = 0.f;
  __syncthreads();
  int total = N*32;
  for (int idx = blockIdx.x*blockDim.x + threadIdx.x; idx < total; idx += gridDim.x*blockDim.x){
    int c4 = (idx & 31)*4;
    float a0 = rs[(c4+0)*RPAD]/(dn[(c4+0)*RPAD]+1e-16f);
    float a1 = rs[(c4+1)*RPAD]/(dn[(c4+1)*RPAD]+1e-16f);
    float a2 = rs[(c4+2)*RPAD]/(dn[(c4+2)*RPAD]+1e-16f);
    float a3 = rs[(c4+3)*RPAD]/(dn[(c4+3)*RPAD]+1e-16f);
    float4 p  = ((const float4*)P)[idx];
    float4 ap = ((const float4*)AP)[idx];
    float4 x  = ((float4*)X)[idx];
    float4 r  = ((float4*)R)[idx];
    x.x += a0*p.x; x.y += a1*p.y; x.z += a2*p.z; x.w += a3*p.w;
    r.x -= a0*ap.x; r.y -= a1*ap.y; r.z -= a2*ap.z; r.w -= a3*ap.w;
    ((float4*)X)[idx] = x; ((float4*)R)[idx] = r;
    atomicAdd(&cols[c4+0], r.x*r.x);
    atomicAdd(&cols[c4+1], r.y*r.y);
    atomicAdd(&cols[c4+2], r.z*r.z);
    atomicAdd(&cols[c4+3], r.w*r.w);
  }
  __syncthreads();
  if (threadIdx.x < 128){ float v = cols[threadIdx.x]; if (v != 0.f) atomicAdd(&rsn[threadIdx.x*RPAD], v); }
}

__global__ void cg_p(const int* __restrict__ flags, int k, const float* __restrict__ rsn, const float* __restrict__ rsp,
                     const float* __restrict__ R, float* __restrict__ P, short* __restrict__ Pbf,
                     int* __restrict__ flags_w){
  if (flags[k]){ if (threadIdx.x==0) flags_w[k+1] = 1; return; }
  __shared__ float red[4];
  __shared__ int done_s;
  float v = (threadIdx.x < 128) ? rsn[threadIdx.x*RPAD] : -1.f;
  #pragma unroll
  for (int d=32; d; d>>=1) v = fmaxf(v, __shfl_xor(v, d));
  if ((threadIdx.x & 63)==0) red[threadIdx.x>>6] = v;
  __syncthreads();
  if (threadIdx.x==0){
    float m = fmaxf(fmaxf(red[0],red[1]), fmaxf(red[2],red[3]));
    done_s = (m < TOL2) ? 1 : 0;
  }
  __syncthreads();
  if (done_s){ if (threadIdx.x==0) flags_w[k+1] = 1; return; }
  int total = N*32;
  for (int idx = blockIdx.x*blockDim.x + threadIdx.x; idx < total; idx += gridDim.x*blockDim.x){
    int c4 = (idx & 31)*4;
    float b0 = rsn[(c4+0)*RPAD]/(rsp[(c4+0)*RPAD]+1e-16f);
    float b1v = rsn[(c4+1)*RPAD]/(rsp[(c4+1)*RPAD]+1e-16f);
    float b2v = rsn[(c4+2)*RPAD]/(rsp[(c4+2)*RPAD]+1e-16f);
    float b3 = rsn[(c4+3)*RPAD]/(rsp[(c4+3)*RPAD]+1e-16f);
    float4 r = ((const float4*)R)[idx];
    float4 p = ((float4*)P)[idx];
    p.x = r.x + b0*p.x; p.y = r.y + b1v*p.y; p.z = r.z + b2v*p.z; p.w = r.w + b3*p.w;
    ((float4*)P)[idx] = p;
    short4 pb; pb.x=f2b(p.x); pb.y=f2b(p.y); pb.z=f2b(p.z); pb.w=f2b(p.w);
    ((short4*)Pbf)[idx] = pb;
  }
}

// ---------------- AFM ----------------
__global__ void isd_kernel(const float* __restrict__ deg, float* __restrict__ isd){
  int i = blockIdx.x*256 + threadIdx.x;
  if (i < N) isd[i] = sqrtf(1.f / fmaxf(deg[i], 1e-8f));
}

// out = alpha*tildeL(Min) - beta*Mprev; gathers bf16 Minb; optional bf16 out
__global__ void tl_apply(const float* __restrict__ Min, const unsigned* __restrict__ Minb,
                         const float* __restrict__ Mprev, float alpha, float beta,
                         const float* __restrict__ isd, const float* __restrict__ deg, const int* __restrict__ offb,
                         const int* __restrict__ adjn, const float* __restrict__ adjw2,
                         float* __restrict__ out, unsigned* __restrict__ outb){
  int wid = threadIdx.x >> 6, lane = threadIdx.x & 63;
  int node = blockIdx.x*4 + wid;
  if (node >= N) return;
  float2 acc = {0.f,0.f};
  int p0 = offb[node], p1 = offb[node+1];
  int p = p0;
  for (; p+8 <= p1; p += 8){
    int jj[8]; float ww[8];
    #pragma unroll
    for (int t=0;t<8;t++){ jj[t] = adjn[p+t]; ww[t] = adjw2[p+t]; }
    unsigned uu[8];
    #pragma unroll
    for (int t=0;t<8;t++) uu[t] = Minb[(long)jj[t]*64 + lane];
    #pragma unroll
    for (int t=0;t<8;t++){ float2 v = ub2f2(uu[t]); acc.x += ww[t]*v.x; acc.y += ww[t]*v.y; }
  }
  for (; p<p1; p++){
    int j = adjn[p]; float w = adjw2[p];
    float2 v = ub2f2(Minb[(long)j*64 + lane]);
    acc.x += w*v.x; acc.y += w*v.y;
  }
  float ii = isd[node]; float dg = deg[node];
  float2 mi = ((const float2*)Min)[(long)node*64 + lane];
  float2 pv = ((const float2*)Mprev)[(long)node*64 + lane];
  float2 o;
  o.x = alpha*(mi.x + ii*(dg*ii*mi.x - acc.x)) - beta*pv.x;
  o.y = alpha*(mi.y + ii*(dg*ii*mi.y - acc.y)) - beta*pv.y;
  ((float2*)out)[(long)node*64 + lane] = o;
  if (outb) outb[(long)node*64 + lane] = pack2(o.x, o.y);
}

__global__ void combine_fused(const float* __restrict__ h, const float* __restrict__ X,
                              const float* __restrict__ T1, const float* __restrict__ T2, const float* __restrict__ T3,
                              const float* __restrict__ gamma, const float* __restrict__ asvr, const float* __restrict__ aafm,
                              short* __restrict__ fusedb){
  float g0=gamma[0], g1=gamma[1], g2=gamma[2], g3=gamma[3];
  float mg = fmaxf(fmaxf(g0,g1), fmaxf(g2,g3));
  float e0=expf(g0-mg), e1=expf(g1-mg), e2=expf(g2-mg), e3=expf(g3-mg);
  float s = e0+e1+e2+e3;
  float a0=e0/s, a1=e1/s, a2=e2/s, a3=e3/s;
  float s1 = 1.f/(1.f+expf(-asvr[0]));
  float s2 = 1.f/(1.f+expf(-aafm[0]));
  int total = N*H;
  for (int i = blockIdx.x*blockDim.x + threadIdx.x; i < total; i += gridDim.x*blockDim.x){
    float hv = h[i];
    float v = hv + s1*X[i] + s2*(a0*hv + a1*T1[i] + a2*T2[i] + a3*T3[i]);
    fusedb[i] = f2b(v);
  }
}

// ---------------- GAT ----------------
__global__ void esed1_kernel(const float* __restrict__ xw1, const float* __restrict__ a1s, const float* __restrict__ a1d,
                             float* __restrict__ es, float* __restrict__ ed){
  int id = blockIdx.x*256 + threadIdx.x;
  if (id < N*8){
    int n = id >> 3, hd = id & 7;
    const float* xr = xw1 + (long)n*64 + hd*8;
    float s=0.f, d=0.f;
    #pragma unroll
    for (int c=0;c<8;c++){ float v = xr[c]; s += v*a1s[hd*8+c]; d += v*a1d[hd*8+c]; }
    es[id]=s; ed[id]=d;
  }
}

// single-pass online-softmax GAT layer 1; gathers bf16 xw1 rows
__global__ void gat1(const int* __restrict__ offi, const int* __restrict__ adjsrc,
                     const float* __restrict__ es, const float* __restrict__ ed,
                     const float* __restrict__ xw1, const unsigned short* __restrict__ xw1b,
                     const float* __restrict__ b1, float* __restrict__ o1){
  int wid = threadIdx.x >> 6, lane = threadIdx.x & 63;
  int d = blockIdx.x*4 + wid;
  if (d >= N) return;
  int hd = lane >> 3;
  float edd = ed[d*8+hd];
  float esd = es[d*8+hd];
  auto lk = [](float x){ return x >= 0.f ? x : 0.2f*x; };
  float m = lk(esd+edd);
  float den = 1.f;
  float num = xw1[(long)d*64 + lane];
  int p0 = offi[d], p1 = offi[d+1];
  int p = p0;
  for (; p+4 <= p1; p += 4){
    int ss[4];
    #pragma unroll
    for (int t=0;t<4;t++) ss[t] = adjsrc[p+t];
    float ee[4]; unsigned short uv[4];
    #pragma unroll
    for (int t=0;t<4;t++){ ee[t] = es[ss[t]*8+hd]; uv[t] = xw1b[(long)ss[t]*64 + lane]; }
    #pragma unroll
    for (int t=0;t<4;t++){
      float e = lk(ee[t]+edd);
      float mn = fmaxf(m, e);
      float sc = expf(m-mn), ex = expf(e-mn);
      den = den*sc + ex;
      num = num*sc + ex*ub2f(uv[t]);
      m = mn;
    }
  }
  for (; p<p1; p++){
    int s = adjsrc[p];
    float e = lk(es[s*8+hd]+edd);
    float v = ub2f(xw1b[(long)s*64 + lane]);
    float mn = fmaxf(m, e);
    float sc = expf(m-mn), ex = expf(e-mn);
    den = den*sc + ex;
    num = num*sc + ex*v;
    m = mn;
  }
  float o = num/(den+1e-16f) + b1[lane];
  o1[(long)d*64+lane] = o > 0.f ? o : expm1f(o);
}

__global__ void xw2_kernel(const float* __restrict__ o1, const float* __restrict__ W2, float* __restrict__ xw2){
  __shared__ float w2s[64*16];
  for (int i=threadIdx.x; i<64*16; i+=256) w2s[i] = W2[i];
  __syncthreads();
  int id = blockIdx.x*256 + threadIdx.x;
  if (id < N*16){
    int n = id >> 4, c = id & 15;
    const float* orow = o1 + (long)n*64;
    float acc = 0.f;
    #pragma unroll
    for (int kk=0; kk<64; kk++) acc += orow[kk]*w2s[kk*16+c];
    xw2[id] = acc;
  }
}

__global__ void esed2_kernel(const float* __restrict__ xw2, const float* __restrict__ a2s, const float* __restrict__ a2d,
                             float* __restrict__ es2, float* __restrict__ ed2){
  int n = blockIdx.x*256 + threadIdx.x;
  if (n < N){
    float s=0.f, d=0.f;
    #pragma unroll
    for (int c=0;c<16;c++){ float v = xw2[(long)n*16+c]; s += v*a2s[c]; d += v*a2d[c]; }
    es2[n]=s; ed2[n]=d;
  }
}

// single-pass online-softmax GAT layer 2 (1 head, 16 ch)
__global__ void gat2(const int* __restrict__ offi, const int* __restrict__ adjsrc,
                     const float* __restrict__ es2, const float* __restrict__ ed2,
                     const float* __restrict__ xw2, const float* __restrict__ b2w, float* __restrict__ out){
  int wid = threadIdx.x >> 6, lane = threadIdx.x & 63;
  int d = blockIdx.x*4 + wid;
  if (d >= N) return;
  auto lk = [](float x){ return x >= 0.f ? x : 0.2f*x; };
  float edd = ed2[d];
  float m = lk(es2[d]+edd);
  float den = 1.f;
  float num = (lane<16) ? xw2[(long)d*16+lane] : 0.f;
  int p0 = offi[d], p1 = offi[d+1];
  int p = p0;
  for (; p+4 <= p1; p += 4){
    int ss[4];
    #pragma unroll
    for (int t=0;t<4;t++) ss[t] = adjsrc[p+t];
    float ee[4], vv[4];
    #pragma unroll
    for (int t=0;t<4;t++){ ee[t] = es2[ss[t]]; vv[t] = (lane<16) ? xw2[(long)ss[t]*16+lane] : 0.f; }
    #pragma unroll
    for (int t=0;t<4;t++){
      float e = lk(ee[t]+edd);
      float mn = fmaxf(m, e);
      float sc = expf(m-mn), ex = expf(e-mn);
      den = den*sc + ex;
      num = num*sc + ex*vv[t];
      m = mn;
    }
  }
  for (; p<p1; p++){
    int s = adjsrc[p];
    float e = lk(es2[s]+edd);
    float v = (lane<16) ? xw2[(long)s*16+lane] : 0.f;
    float mn = fmaxf(m, e);
    float sc = expf(m-mn), ex = expf(e-mn);
    den = den*sc + ex;
    num = num*sc + ex*v;
    m = mn;
  }
  if (lane<16) out[(long)d*16+lane] = num/(den+1e-16f) + b2w[lane];
}

// ---------------- host ----------------
extern "C" void kernel_launch(void* const* d_in, const int* in_sizes, int n_in,
                              void* d_out, int out_size, void* d_ws, size_t ws_size,
                              hipStream_t stream){
  const float* x     = (const float*)d_in[0];
  const int*   ei    = (const int*)  d_in[1];
  const float* W_in  = (const float*)d_in[2];
  const float* b_in  = (const float*)d_in[3];
  const float* ln_g  = (const float*)d_in[4];
  const float* ln_b  = (const float*)d_in[5];
  const float* W_sh  = (const float*)d_in[6];
  const float* gamma = (const float*)d_in[7];
  const float* asvr  = (const float*)d_in[8];
  const float* aafm  = (const float*)d_in[9];
  const float* W1    = (const float*)d_in[10];
  const float* a1s   = (const float*)d_in[11];
  const float* a1d   = (const float*)d_in[12];
  const float* b1    = (const float*)d_in[13];
  const float* W2    = (const float*)d_in[14];
  const float* a2s   = (const float*)d_in[15];
  const float* a2d   = (const float*)d_in[16];
  const float* b2w   = (const float*)d_in[17];

  char* ws = (char*)d_ws;
  size_t off = 0;
  auto alloc = [&](size_t bytes)->char*{ char* p = ws + off; off = (off + bytes + 255) & ~(size_t)255; return p; };
  float* h    = (float*)alloc((size_t)N*H*4);
  float* big1 = (float*)alloc((size_t)N*H*4); // preLN -> hw(f32, unused) -> AP -> T3
  float* X    = (float*)alloc((size_t)N*H*4);
  float* Rb   = (float*)alloc((size_t)N*H*4); // R -> T1
  float* Pb   = (float*)alloc((size_t)N*H*4); // P -> T2
  short* hbf  = (short*)alloc((size_t)N*H*2); // bf16(h): gemm input + tl1 gather
  short* fusedb = (short*)alloc((size_t)N*H*2);
  short* bufA = (short*)alloc((size_t)N*H*2); // hwb -> Pbf -> T1b
  short* bufB = (short*)alloc((size_t)N*H*2); // T2b -> xw1b
  float* wLp  = (float*)alloc((size_t)E*4);
  float* deg  = (float*)alloc((size_t)N*4);
  float* isd  = (float*)alloc((size_t)N*4);
  int* cntb   = (int*)alloc((size_t)N*4);
  int* cnti   = (int*)alloc((size_t)N*4);
  int* offb   = (int*)alloc((size_t)(N+1)*4);
  int* offi   = (int*)alloc((size_t)(N+1)*4);
  int* adjn   = (int*)alloc((size_t)2*E*4);
  int* adjeid = (int*)alloc((size_t)2*E*4);
  float* adjw = (float*)alloc((size_t)2*E*4);
  int* adjsrc = (int*)alloc((size_t)E*4);
  short* BtIn = (short*)alloc((size_t)IN*H*2);
  short* Wst  = (short*)alloc((size_t)H*H*2);
  short* W1t  = (short*)alloc((size_t)H*64*2);
  float* rs_all = (float*)alloc((size_t)(MAXITER+1)*128*RPAD*4);
  float* dn_all = (float*)alloc((size_t)MAXITER*128*RPAD*4);
  int* flags  = (int*)alloc((size_t)(MAXITER+1)*4);

  // aliases (regions dead by the time these are written)
  short* xbf = (short*)X;               // N*IN bf16 = 51.2MB, spans X+Rb (dead until cg_init)
  float* adjw2 = (float*)adjeid;        // adjeid dead after adj_weights
  short* hwb  = bufA;                   // bf16 hw: gemm<H,H> -> edge_weights
  short* Pbf  = bufA;                   // CG bf16 P: cg_init -> CG end
  short* T1b  = bufA;                   // tl1 -> tl2
  short* T2b  = bufB;                   // tl2 -> tl3
  short* xw1b = bufB;                   // gemm<H,64> -> gat1
  float* xw1 = h;                       // after combine, h region reused
  float* o1  = h + (size_t)N*64;
  float* es  = X;                       // after combine, X region reused
  float* ed  = X + (size_t)N*8;
  float* xw2 = X + (size_t)N*16;
  float* es2 = X + (size_t)N*32;
  float* ed2 = X + (size_t)N*33;
  float* AP  = big1;
  float* T1 = Rb; float* T2 = Pb; float* T3 = big1;

  hipMemsetAsync(deg, 0, (size_t)N*4, stream);
  hipMemsetAsync(cntb, 0, (size_t)N*4, stream);
  hipMemsetAsync(cnti, 0, (size_t)N*4, stream);
  hipMemsetAsync(rs_all, 0, (size_t)(MAXITER+1)*128*RPAD*4, stream);
  hipMemsetAsync(dn_all, 0, (size_t)MAXITER*128*RPAD*4, stream);
  hipMemsetAsync(flags, 0, (size_t)(MAXITER+1)*4, stream);

  conv_x<<<(int)(((long)N*IN/4 + 255)/256),256,0,stream>>>(x, xbf, (long)N*IN/4);
  conv_transpose<<<(IN*H+255)/256,256,0,stream>>>(W_in, BtIn, IN, H);
  conv_transpose<<<(H*H+255)/256,256,0,stream>>>(W_sh, Wst, H, H);
  conv_transpose<<<(H*64+255)/256,256,0,stream>>>(W1, W1t, H, 64);

  int gm = (N+63)/64;
  mfma_gemm<IN,H,false><<<gm,256,0,stream>>>(xbf, BtIn, big1, nullptr, N);
  ln_sigmoid<<<N,128,0,stream>>>(big1, b_in, ln_g, ln_b, h, hbf);
  mfma_gemm<H,H,true><<<gm,256,0,stream>>>(hbf, Wst, big1, hwb, N);

  count_deg<<<(E+255)/256,256,0,stream>>>(ei, cntb, cnti);
  scan_excl<<<1,1024,0,stream>>>(cntb, N, offb);
  scan_excl<<<1,1024,0,stream>>>(cnti, N, offi);
  hipMemsetAsync(cntb, 0, (size_t)N*4, stream);
  hipMemsetAsync(cnti, 0, (size_t)N*4, stream);
  fill_adj<<<(E+255)/256,256,0,stream>>>(ei, offb, offi, cntb, cnti, adjn, adjeid, adjsrc);

  edge_weights<<<(E+3)/4,256,0,stream>>>(ei, (const unsigned*)hwb, wLp, deg);
  adj_weights<<<(2*E+255)/256,256,0,stream>>>(adjeid, wLp, adjw);

  cg_init<<<1024,256,0,stream>>>(h, X, Rb, Pb, Pbf, rs_all);
  for (int k=0; k<MAXITER; k++){
    cg_ap<<<1024,256,0,stream>>>(flags, k, Pb, (const unsigned*)Pbf, offb, adjn, adjw, deg, AP, dn_all+(size_t)k*128*RPAD);
    cg_xr<<<1024,256,0,stream>>>(flags, k, rs_all+(size_t)k*128*RPAD, dn_all+(size_t)k*128*RPAD, Pb, AP, X, Rb, rs_all+(size_t)(k+1)*128*RPAD);
    cg_p<<<1024,256,0,stream>>>(flags, k, rs_all+(size_t)(k+1)*128*RPAD, rs_all+(size_t)k*128*RPAD, Rb, Pb, Pbf, flags);
  }

  isd_kernel<<<(N+255)/256,256,0,stream>>>(deg, isd);
  adj_w_isd<<<(2*E+255)/256,256,0,stream>>>(adjn, adjw, isd, adjw2);
  tl_apply<<<(N+3)/4,256,0,stream>>>(h,  (const unsigned*)hbf, h,  1.f, 0.f, isd, deg, offb, adjn, adjw2, T1, (unsigned*)T1b);
  tl_apply<<<(N+3)/4,256,0,stream>>>(T1, (const unsigned*)T1b, h,  2.f, 1.f, isd, deg, offb, adjn, adjw2, T2, (unsigned*)T2b);
  tl_apply<<<(N+3)/4,256,0,stream>>>(T2, (const unsigned*)T2b, T1, 2.f, 1.f, isd, deg, offb, adjn, adjw2, T3, nullptr);
  combine_fused<<<1024,256,0,stream>>>(h, X, T1, T2, T3, gamma, asvr, aafm, fusedb);

  mfma_gemm<H,64,true><<<gm,256,0,stream>>>(fusedb, W1t, xw1, xw1b, N);
  esed1_kernel<<<(N*8+255)/256,256,0,stream>>>(xw1, a1s, a1d, es, ed);
  gat1<<<(N+3)/4,256,0,stream>>>(offi, adjsrc, es, ed, xw1, (const unsigned short*)xw1b, b1, o1);
  xw2_kernel<<<(N*16+255)/256,256,0,stream>>>(o1, W2, xw2);
  esed2_kernel<<<(N+255)/256,256,0,stream>>>(xw2, a2s, a2d, es2, ed2);
  gat2<<<(N+3)/4,256,0,stream>>>(offi, adjsrc, es2, ed2, xw2, b2w, (float*)d_out);
}